// Round 1
// baseline (409.304 us; speedup 1.0000x reference)
//
#include <hip/hip_runtime.h>
#include <math.h>

#define D 128
#define L 50
#define SCALE 0.08838834764831845f   // 1/sqrt(128)

// ---------------------------------------------------------------------------
// Kernel A: uh = user @ W_user, ih = item @ W_item  (f32, one block per row)
// ---------------------------------------------------------------------------
__global__ __launch_bounds__(D) void proj_kernel(
    const float* __restrict__ user, const float* __restrict__ item,
    const float* __restrict__ Wu,   const float* __restrict__ Wi,
    float* __restrict__ uh, float* __restrict__ ih, int NU, int NI)
{
    __shared__ float srow[D];
    int b = blockIdx.x;
    int t = threadIdx.x;
    const float* src; const float* W; float* dst; int r;
    if (b < NU) { src = user; W = Wu; dst = uh; r = b; }
    else        { src = item; W = Wi; dst = ih; r = b - NU; }
    srow[t] = src[(size_t)r * D + t];
    __syncthreads();
    float acc = 0.f;
    #pragma unroll 8
    for (int k = 0; k < D; ++k) acc += srow[k] * W[k * D + t];
    dst[(size_t)r * D + t] = acc;
}

// ---------------------------------------------------------------------------
// Kernel B: fused per-node aggregation + gate + update + tanh.
// One 128-thread block per node; blocks [0,NU) do users, [NU,NU+NI) items.
// ---------------------------------------------------------------------------
__global__ __launch_bounds__(D) void agg_kernel(
    const float* __restrict__ uh,     const float* __restrict__ ih,
    const float* __restrict__ user,   const float* __restrict__ item,
    const float* __restrict__ gate_u, const float* __restrict__ gate_i,
    const float* __restrict__ upd_u,  const float* __restrict__ upd_i,
    const float* __restrict__ uemb,   const float* __restrict__ uembk,
    const float* __restrict__ iemb,   const float* __restrict__ iembk,
    const int* __restrict__ unbr,     const int* __restrict__ untime,
    const int* __restrict__ inbr,     const int* __restrict__ intime,
    float* __restrict__ out, int NU, int NI)
{
    __shared__ float smail[L][D + 1];      // 50 x 129 floats, 2-way bank alias only
    __shared__ float sh[D], sraw[D], scat[2 * D], sagg[D];
    __shared__ float se[L], se1[L], salpha[L], salpha1[L], seproj[L];
    __shared__ int   stime[L], sreorder[L], snbr[L], slast;

    int b = blockIdx.x, t = threadIdx.x;
    const float *dstH, *mail, *raw, *emb, *embk, *gate, *upd;
    const int *nbr, *tim; float* o; int n;
    if (b < NU) {
        n = b;      dstH = uh; mail = ih; raw = user;
        emb = uemb; embk = uembk; gate = gate_u; upd = upd_u;
        nbr = unbr; tim = untime; o = out;
    } else {
        n = b - NU; dstH = ih; mail = uh; raw = item;
        emb = iemb; embk = iembk; gate = gate_i; upd = upd_i;
        nbr = inbr; tim = intime; o = out + (size_t)NU * D;
    }

    // ---- S0: load dst hidden, raw feature, time row, neighbor row ----
    sh[t]   = dstH[(size_t)n * D + t];
    sraw[t] = raw [(size_t)n * D + t];
    if (t < L) { stime[t] = tim[n * L + t]; snbr[t] = nbr[n * L + t]; }
    __syncthreads();

    // ---- S1: ranks (stable argsort∘argsort), argmax(first), eproj, stage mail
    if (t < L) {
        int ti = stime[t]; int rank = 0;
        for (int j = 0; j < L; ++j) {
            int tj = stime[j];
            rank += (tj < ti) || (tj == ti && j < t);   // stable-sort rank
        }
        sreorder[t] = L - 1 - rank;
        float a = 0.f;
        const float* er = emb + t * D;
        for (int j = 0; j < D; ++j) a += er[j] * sh[j];
        seproj[t] = a;
    }
    if (t == 0) {
        int mv = stime[0], mi = 0;
        for (int j = 1; j < L; ++j) if (stime[j] > mv) { mv = stime[j]; mi = j; }
        slast = mi;                                     // first occurrence of max
    }
    for (int l = 0; l < L; ++l)
        smail[l][t] = mail[(size_t)snbr[l] * D + t];    // coalesced 512B rows
    __syncthreads();

    // ---- S2: long-term scores e and short-term scores e1 ----
    if (t < L) {
        float a = 0.f, a1 = 0.f;
        int lastIdx = slast;
        for (int j = 0; j < D; ++j) {
            float mj = smail[t][j];
            a  += mj * sh[j];
            a1 += mj * smail[lastIdx][j];               // broadcast read
        }
        se[t]  = (a + seproj[sreorder[t]]) * SCALE;
        se1[t] = a1 * SCALE;
    }
    __syncthreads();

    // ---- S3: softmax numerators (max via redundant per-thread loop) ----
    float m = -1e30f, m1 = -1e30f;
    for (int l = 0; l < L; ++l) {
        m  = fmaxf(m,  se[l]);
        m1 = fmaxf(m1, se1[l]);
    }
    if (t < L) {
        salpha[t]  = expf(se[t]  - m);
        salpha1[t] = expf(se1[t] - m1);
    }
    __syncthreads();

    // ---- S4: softmax denominators + weighted sums (each thread owns dim t)
    float s = 0.f, s1 = 0.f;
    for (int l = 0; l < L; ++l) { s += salpha[l]; s1 += salpha1[l]; }
    float inv = 1.f / s, inv1 = 1.f / s1;
    float hl = 0.f, hs = 0.f;
    for (int l = 0; l < L; ++l) {
        float ml = smail[l][t];
        hl += salpha[l]  * (ml + embk[sreorder[l] * D + t]);
        hs += salpha1[l] * ml;
    }
    scat[t]     = hl * inv;
    scat[D + t] = hs * inv1;
    __syncthreads();

    // ---- S5: gate GEMV  agg = [h_long, h_short] @ gate_W ----
    {
        float a = 0.f;
        #pragma unroll 8
        for (int k = 0; k < 2 * D; ++k) a += scat[k] * gate[k * D + t];
        sagg[t] = a;
    }
    __syncthreads();

    // ---- S6: update GEMV + tanh  out = tanh([agg, raw] @ update) ----
    {
        float p = 0.f;
        #pragma unroll 8
        for (int k = 0; k < D; ++k)
            p += sagg[k] * upd[k * D + t] + sraw[k] * upd[(k + D) * D + t];
        o[(size_t)n * D + t] = tanhf(p);
    }
}

// ---------------------------------------------------------------------------
extern "C" void kernel_launch(void* const* d_in, const int* in_sizes, int n_in,
                              void* d_out, int out_size, void* d_ws, size_t ws_size,
                              hipStream_t stream) {
    const float* user   = (const float*)d_in[0];
    const float* item   = (const float*)d_in[1];
    const float* Wu     = (const float*)d_in[2];
    const float* Wi     = (const float*)d_in[3];
    const float* gate_u = (const float*)d_in[4];
    const float* gate_i = (const float*)d_in[5];
    const float* upd_u  = (const float*)d_in[6];
    const float* upd_i  = (const float*)d_in[7];
    const float* uemb   = (const float*)d_in[8];
    const float* uembk  = (const float*)d_in[9];
    const float* iemb   = (const float*)d_in[10];
    const float* iembk  = (const float*)d_in[11];
    const int*   unbr   = (const int*)d_in[12];
    const int*   untime = (const int*)d_in[13];
    const int*   inbr   = (const int*)d_in[14];
    const int*   intime = (const int*)d_in[15];

    int NU = in_sizes[0] / D;
    int NI = in_sizes[1] / D;

    float* uh = (float*)d_ws;                // NU*D f32
    float* ih = uh + (size_t)NU * D;         // NI*D f32
    float* out = (float*)d_out;              // [NU*D] user_out, then [NI*D] item_out

    proj_kernel<<<NU + NI, D, 0, stream>>>(user, item, Wu, Wi, uh, ih, NU, NI);
    agg_kernel<<<NU + NI, D, 0, stream>>>(uh, ih, user, item,
                                          gate_u, gate_i, upd_u, upd_i,
                                          uemb, uembk, iemb, iembk,
                                          unbr, untime, inbr, intime,
                                          out, NU, NI);
}

// Round 2
// 296.855 us; speedup vs baseline: 1.3788x; 1.3788x over previous
//
#include <hip/hip_runtime.h>
#include <math.h>

#define D 128
#define L 50
#define SCALE 0.08838834764831845f   // 1/sqrt(128)

// ---------------------------------------------------------------------------
// prep: WE_s = W_s @ emb_s^T  (128x50);  EKG_s = embk_s @ gate_s[0:128] (50x128)
// 4 matrices x 6400 outputs; 25 blocks each, 1 output/thread, 128-MAC loop.
// ---------------------------------------------------------------------------
__global__ __launch_bounds__(256) void prep_kernel(
    const float* __restrict__ Wu, const float* __restrict__ Wi,
    const float* __restrict__ gu, const float* __restrict__ gi,
    const float* __restrict__ ue, const float* __restrict__ ie,
    const float* __restrict__ uek, const float* __restrict__ iek,
    float* __restrict__ WEu, float* __restrict__ WEi,
    float* __restrict__ EKGu, float* __restrict__ EKGi)
{
    int mat = blockIdx.x / 25;
    int o = (blockIdx.x % 25) * 256 + threadIdx.x;
    if (o >= D * L) return;
    if (mat < 2) {
        const float* W = mat ? Wi : Wu;
        const float* E = mat ? ie : ue;
        float* C       = mat ? WEi : WEu;
        int d = o / L, l = o % L;
        float a = 0.f;
        for (int k = 0; k < D; ++k) a += W[d * D + k] * E[l * D + k];
        C[d * L + l] = a;                         // WE[d][l]
    } else {
        const float* G  = (mat == 3) ? gi : gu;   // use top 128 rows
        const float* EK = (mat == 3) ? iek : uek;
        float* C        = (mat == 3) ? EKGi : EKGu;
        int r = o / D, c = o % D;
        float a = 0.f;
        for (int k = 0; k < D; ++k) a += EK[r * D + k] * G[k * D + c];
        C[r * D + c] = a;                         // EKG[r][c]
    }
}

// ---------------------------------------------------------------------------
// proj: per 8 nodes, h = x @ W (cols 0..127) and eproj = x @ WE (cols 128..177)
// 192 threads; x rows staged transposed in LDS for float4 broadcast reads.
// ---------------------------------------------------------------------------
__global__ __launch_bounds__(192) void proj_kernel(
    const float* __restrict__ user, const float* __restrict__ item,
    const float* __restrict__ Wu, const float* __restrict__ Wi,
    const float* __restrict__ WEu, const float* __restrict__ WEi,
    float* __restrict__ h, float* __restrict__ eproj, int NU, int NI)
{
    __shared__ float srowT[D][8];                 // srowT[k][r], 4 KB, 16B rows
    int b = blockIdx.x, t = threadIdx.x;
    int nblk_u = NU / 8;
    const float* X; const float* W; const float* WE; int n0, base;
    if (b < nblk_u) { X = user; W = Wu; WE = WEu; n0 = b * 8;            base = 0; }
    else            { X = item; W = Wi; WE = WEi; n0 = (b - nblk_u) * 8; base = NU; }

    if (t < D)
        for (int r = 0; r < 8; ++r) srowT[t][r] = X[(size_t)(n0 + r) * D + t];
    __syncthreads();

    if (t < D + L) {
        const float* wp; int wstride;
        if (t < D) { wp = W + t;        wstride = D; }
        else       { wp = WE + (t - D); wstride = L; }
        float acc[8] = {0, 0, 0, 0, 0, 0, 0, 0};
        for (int k = 0; k < D; ++k) {
            float w  = wp[(size_t)k * wstride];
            float4 a0 = *(const float4*)&srowT[k][0];
            float4 a1 = *(const float4*)&srowT[k][4];
            acc[0] += a0.x * w; acc[1] += a0.y * w; acc[2] += a0.z * w; acc[3] += a0.w * w;
            acc[4] += a1.x * w; acc[5] += a1.y * w; acc[6] += a1.z * w; acc[7] += a1.w * w;
        }
        if (t < D) {
            for (int r = 0; r < 8; ++r) h[(size_t)(base + n0 + r) * D + t] = acc[r];
        } else {
            int l = t - D;
            for (int r = 0; r < 8; ++r) eproj[(size_t)(base + n0 + r) * L + l] = acc[r];
        }
    }
}

// ---------------------------------------------------------------------------
// agg: gather mailbox + ranks + both attentions; writes scat=[hl|hs|beta|0] (320)
// ---------------------------------------------------------------------------
__global__ __launch_bounds__(128) void agg_kernel(
    const float* __restrict__ h, const float* __restrict__ eproj,
    const int* __restrict__ unbr, const int* __restrict__ untime,
    const int* __restrict__ inbr, const int* __restrict__ intime,
    float* __restrict__ scat, int NU, int NI)
{
    __shared__ float smail[L][D + 1];             // stride 129: 2-way alias only
    __shared__ float sh[D];
    __shared__ float se[L], se1[L], salpha[L], salpha1[L];
    __shared__ int stime[L], sreorder[L], snbr[L], slast;

    int g = blockIdx.x, t = threadIdx.x;
    const float* mail; const int* nbrp; const int* timp;
    if (g < NU) { mail = h + (size_t)NU * D; nbrp = unbr + (size_t)g * L;        timp = untime + (size_t)g * L; }
    else        { mail = h;                  nbrp = inbr + (size_t)(g - NU) * L; timp = intime + (size_t)(g - NU) * L; }

    sh[t] = h[(size_t)g * D + t];
    if (t < L) { stime[t] = timp[t]; snbr[t] = nbrp[t]; }
    __syncthreads();

    // ranks (stable argsort∘argsort) + first-occurrence argmax
    if (t < L) {
        int ti = stime[t]; int rank = 0; bool firstmax = true;
        for (int j = 0; j < L; ++j) {
            int tj = stime[j];
            rank += (tj < ti) || (tj == ti && j < t);
            firstmax = firstmax && ((tj < ti) || (tj == ti && j >= t));
        }
        sreorder[t] = L - 1 - rank;
        if (firstmax) slast = t;
    }
    // stage mail: float4, 4 rows per iteration
    {
        int q = t >> 5, lane = t & 31, c = lane * 4;
        for (int i = 0; i < 13; ++i) {
            int l = i * 4 + q;
            if (l < L) {
                float4 v = *(const float4*)&mail[(size_t)snbr[l] * D + c];
                smail[l][c] = v.x; smail[l][c + 1] = v.y;
                smail[l][c + 2] = v.z; smail[l][c + 3] = v.w;
            }
        }
    }
    __syncthreads();

    // scores: wave0 -> long-term, wave1 -> short-term
    {
        int w = t >> 6, lane = t & 63;
        if (lane < L) {
            if (w == 0) {
                float a = 0.f;
                for (int j = 0; j < D; ++j) a += smail[lane][j] * sh[j];
                se[lane] = (a + eproj[(size_t)g * L + sreorder[lane]]) * SCALE;
            } else {
                const float* lastrow = smail[slast];
                float a1 = 0.f;
                for (int j = 0; j < D; ++j) a1 += smail[lane][j] * lastrow[j];
                se1[lane] = a1 * SCALE;
            }
        }
    }
    __syncthreads();

    float m = -1e30f, m1 = -1e30f;
    for (int l = 0; l < L; ++l) { m = fmaxf(m, se[l]); m1 = fmaxf(m1, se1[l]); }
    if (t < L) { salpha[t] = expf(se[t] - m); salpha1[t] = expf(se1[t] - m1); }
    __syncthreads();

    float s = 0.f, s1 = 0.f;
    for (int l = 0; l < L; ++l) { s += salpha[l]; s1 += salpha1[l]; }
    float inv = 1.f / s, inv1 = 1.f / s1;
    float hl = 0.f, hs = 0.f;
    for (int l = 0; l < L; ++l) {
        float ml = smail[l][t];
        hl += salpha[l] * ml;
        hs += salpha1[l] * ml;
    }
    float* srow = scat + (size_t)g * 320;
    srow[t]     = hl * inv;
    srow[D + t] = hs * inv1;
    if (t < L)       srow[256 + sreorder[t]] = salpha[t] * inv;  // beta (permuted)
    else if (t < 64) srow[256 + t] = 0.f;                        // pad 306..319
}

// ---------------------------------------------------------------------------
// gemm_gate: aggall = scat @ [gate(256) ; EKG(50) ; 0(14)]   (K=320)
// 32 rows x 128 cols per block, 256 threads, 2x8 micro-tile.
// ---------------------------------------------------------------------------
__global__ __launch_bounds__(256) void gemm_gate(
    const float* __restrict__ scat,
    const float* __restrict__ gate_u, const float* __restrict__ gate_i,
    const float* __restrict__ EKGu,   const float* __restrict__ EKGi,
    float* __restrict__ aggall, int NU)
{
    __shared__ float AcT[32][34];                 // AcT[kk][r]
    __shared__ float Bc[32][132];
    int t = threadIdx.x;
    int nb = blockIdx.x * 32;
    const float* gate = (nb < NU) ? gate_u : gate_i;
    const float* ekg  = (nb < NU) ? EKGu   : EKGi;
    int tx = t & 15, ty = t >> 4;                 // col grp 0..15, row grp 0..15
    float acc[2][8];
    for (int i = 0; i < 2; ++i)
        for (int j = 0; j < 8; ++j) acc[i][j] = 0.f;

    int sr = t >> 3, sj = t & 7;                  // staging: row 0..31, quad 0..7
    for (int kc = 0; kc < 10; ++kc) {
        int K0 = kc * 32;
        // A: coalesced float4 load, transpose into LDS
        {
            float4 v = *(const float4*)&scat[(size_t)(nb + sr) * 320 + K0 + sj * 4];
            AcT[sj * 4 + 0][sr] = v.x; AcT[sj * 4 + 1][sr] = v.y;
            AcT[sj * 4 + 2][sr] = v.z; AcT[sj * 4 + 3][sr] = v.w;
        }
        // B: rows k<256 gate, 256..305 EKG, else 0
        {
            int k = K0 + sr, cb = sj * 16;
            const float* Brow = nullptr;
            if (k < 256)      Brow = gate + (size_t)k * D;
            else if (k < 306) Brow = ekg + (size_t)(k - 256) * D;
            for (int q = 0; q < 4; ++q) {
                float4 v = Brow ? *(const float4*)&Brow[cb + q * 4]
                                : make_float4(0.f, 0.f, 0.f, 0.f);
                *(float4*)&Bc[sr][cb + q * 4] = v;
            }
        }
        __syncthreads();
        for (int kk = 0; kk < 32; ++kk) {
            float2 av = *(const float2*)&AcT[kk][ty * 2];
            float4 b0 = *(const float4*)&Bc[kk][tx * 8];
            float4 b1 = *(const float4*)&Bc[kk][tx * 8 + 4];
            acc[0][0] += av.x * b0.x; acc[0][1] += av.x * b0.y;
            acc[0][2] += av.x * b0.z; acc[0][3] += av.x * b0.w;
            acc[0][4] += av.x * b1.x; acc[0][5] += av.x * b1.y;
            acc[0][6] += av.x * b1.z; acc[0][7] += av.x * b1.w;
            acc[1][0] += av.y * b0.x; acc[1][1] += av.y * b0.y;
            acc[1][2] += av.y * b0.z; acc[1][3] += av.y * b0.w;
            acc[1][4] += av.y * b1.x; acc[1][5] += av.y * b1.y;
            acc[1][6] += av.y * b1.z; acc[1][7] += av.y * b1.w;
        }
        __syncthreads();
    }
    for (int i = 0; i < 2; ++i) {
        size_t n = nb + ty * 2 + i;
        *(float4*)&aggall[n * D + tx * 8]     = make_float4(acc[i][0], acc[i][1], acc[i][2], acc[i][3]);
        *(float4*)&aggall[n * D + tx * 8 + 4] = make_float4(acc[i][4], acc[i][5], acc[i][6], acc[i][7]);
    }
}

// ---------------------------------------------------------------------------
// gemm_upd: out = tanh([aggall | x] @ upd)   (K=256)
// ---------------------------------------------------------------------------
__global__ __launch_bounds__(256) void gemm_upd(
    const float* __restrict__ aggall,
    const float* __restrict__ user, const float* __restrict__ item,
    const float* __restrict__ upd_u, const float* __restrict__ upd_i,
    float* __restrict__ out, int NU)
{
    __shared__ float AcT[32][34];
    __shared__ float Bc[32][132];
    int t = threadIdx.x;
    int nb = blockIdx.x * 32;
    const float* upd = (nb < NU) ? upd_u : upd_i;
    const float* X   = (nb < NU) ? user  : item;
    int xoff = (nb < NU) ? 0 : NU;
    int tx = t & 15, ty = t >> 4;
    float acc[2][8];
    for (int i = 0; i < 2; ++i)
        for (int j = 0; j < 8; ++j) acc[i][j] = 0.f;

    int sr = t >> 3, sj = t & 7;
    for (int kc = 0; kc < 8; ++kc) {
        int K0 = kc * 32;
        {
            int n = nb + sr, k4 = K0 + sj * 4;
            float4 v = (K0 < 128)
                ? *(const float4*)&aggall[(size_t)n * D + k4]
                : *(const float4*)&X[(size_t)(n - xoff) * D + (k4 - 128)];
            AcT[sj * 4 + 0][sr] = v.x; AcT[sj * 4 + 1][sr] = v.y;
            AcT[sj * 4 + 2][sr] = v.z; AcT[sj * 4 + 3][sr] = v.w;
        }
        {
            int k = K0 + sr, cb = sj * 16;
            const float* Brow = upd + (size_t)k * D;
            for (int q = 0; q < 4; ++q)
                *(float4*)&Bc[sr][cb + q * 4] = *(const float4*)&Brow[cb + q * 4];
        }
        __syncthreads();
        for (int kk = 0; kk < 32; ++kk) {
            float2 av = *(const float2*)&AcT[kk][ty * 2];
            float4 b0 = *(const float4*)&Bc[kk][tx * 8];
            float4 b1 = *(const float4*)&Bc[kk][tx * 8 + 4];
            acc[0][0] += av.x * b0.x; acc[0][1] += av.x * b0.y;
            acc[0][2] += av.x * b0.z; acc[0][3] += av.x * b0.w;
            acc[0][4] += av.x * b1.x; acc[0][5] += av.x * b1.y;
            acc[0][6] += av.x * b1.z; acc[0][7] += av.x * b1.w;
            acc[1][0] += av.y * b0.x; acc[1][1] += av.y * b0.y;
            acc[1][2] += av.y * b0.z; acc[1][3] += av.y * b0.w;
            acc[1][4] += av.y * b1.x; acc[1][5] += av.y * b1.y;
            acc[1][6] += av.y * b1.z; acc[1][7] += av.y * b1.w;
        }
        __syncthreads();
    }
    for (int i = 0; i < 2; ++i) {
        size_t n = nb + ty * 2 + i;
        *(float4*)&out[n * D + tx * 8] = make_float4(
            tanhf(acc[i][0]), tanhf(acc[i][1]), tanhf(acc[i][2]), tanhf(acc[i][3]));
        *(float4*)&out[n * D + tx * 8 + 4] = make_float4(
            tanhf(acc[i][4]), tanhf(acc[i][5]), tanhf(acc[i][6]), tanhf(acc[i][7]));
    }
}

// ---------------------------------------------------------------------------
extern "C" void kernel_launch(void* const* d_in, const int* in_sizes, int n_in,
                              void* d_out, int out_size, void* d_ws, size_t ws_size,
                              hipStream_t stream) {
    const float* user   = (const float*)d_in[0];
    const float* item   = (const float*)d_in[1];
    const float* Wu     = (const float*)d_in[2];
    const float* Wi     = (const float*)d_in[3];
    const float* gate_u = (const float*)d_in[4];
    const float* gate_i = (const float*)d_in[5];
    const float* upd_u  = (const float*)d_in[6];
    const float* upd_i  = (const float*)d_in[7];
    const float* uemb   = (const float*)d_in[8];
    const float* uembk  = (const float*)d_in[9];
    const float* iemb   = (const float*)d_in[10];
    const float* iembk  = (const float*)d_in[11];
    const int*   unbr   = (const int*)d_in[12];
    const int*   untime = (const int*)d_in[13];
    const int*   inbr   = (const int*)d_in[14];
    const int*   intime = (const int*)d_in[15];

    int NU = in_sizes[0] / D;
    int NI = in_sizes[1] / D;
    int N  = NU + NI;

    float* h     = (float*)d_ws;                    // N*D     (reused as aggall)
    float* eproj = h + (size_t)N * D;               // N*L
    float* scat  = eproj + (size_t)N * L;           // N*320
    float* WEu   = scat + (size_t)N * 320;          // D*L
    float* WEi   = WEu + D * L;
    float* EKGu  = WEi + D * L;                     // L*D
    float* EKGi  = EKGu + L * D;
    float* aggall = h;                              // alias: h dead after agg

    prep_kernel<<<100, 256, 0, stream>>>(Wu, Wi, gate_u, gate_i, uemb, iemb,
                                         uembk, iembk, WEu, WEi, EKGu, EKGi);
    proj_kernel<<<N / 8, 192, 0, stream>>>(user, item, Wu, Wi, WEu, WEi,
                                           h, eproj, NU, NI);
    agg_kernel<<<N, 128, 0, stream>>>(h, eproj, unbr, untime, inbr, intime,
                                      scat, NU, NI);
    gemm_gate<<<N / 32, 256, 0, stream>>>(scat, gate_u, gate_i, EKGu, EKGi,
                                          aggall, NU);
    gemm_upd<<<N / 32, 256, 0, stream>>>(aggall, user, item, upd_u, upd_i,
                                         (float*)d_out, NU);
}

// Round 3
// 247.709 us; speedup vs baseline: 1.6524x; 1.1984x over previous
//
#include <hip/hip_runtime.h>
#include <math.h>

#define D 128
#define L 50
#define SCALE 0.08838834764831845f   // 1/sqrt(128)

// ---- bf16 pack/unpack helpers (RNE) ---------------------------------------
__device__ __forceinline__ unsigned f2bf(float x) {
    union { float f; unsigned u; } v; v.f = x;
    return (v.u + 0x7fffu + ((v.u >> 16) & 1u)) >> 16;
}
__device__ __forceinline__ float bflo(unsigned u) {
    union { unsigned u; float f; } v; v.u = u << 16; return v.f;
}
__device__ __forceinline__ float bfhi(unsigned u) {
    union { unsigned u; float f; } v; v.u = u & 0xffff0000u; return v.f;
}

// ---------------------------------------------------------------------------
// prep1: WE_s = W_s @ emb_s^T (128x50);  GU_s = gate_s @ upd_s[0:128] (256x128)
// blocks 0..49 WE (25/side), 50..305 GU (128/side). 1 output/thread.
// ---------------------------------------------------------------------------
__global__ __launch_bounds__(256) void prep1_kernel(
    const float* __restrict__ Wu, const float* __restrict__ Wi,
    const float* __restrict__ ue, const float* __restrict__ ie,
    const float* __restrict__ gu, const float* __restrict__ gi,
    const float* __restrict__ uu, const float* __restrict__ ui,
    float* __restrict__ WEu, float* __restrict__ WEi,
    float* __restrict__ GUu, float* __restrict__ GUi)
{
    int b = blockIdx.x, t = threadIdx.x;
    if (b < 50) {
        int side = b / 25;
        int o = (b % 25) * 256 + t;                 // < 6400
        int d = o / L, l = o % L;
        const float* W = side ? Wi : Wu;
        const float* E = side ? ie : ue;
        float* C       = side ? WEi : WEu;
        float a = 0.f;
        for (int k = 0; k < D; ++k) a += W[d * D + k] * E[l * D + k];
        C[d * L + l] = a;
    } else {
        int bb = b - 50;
        int side = bb / 128;
        int o = (bb % 128) * 256 + t;               // < 32768
        int r = o >> 7, c = o & 127;
        const float* G = side ? gi : gu;
        const float* U = side ? ui : uu;
        float* C       = side ? GUi : GUu;
        float a = 0.f;
        for (int k = 0; k < D; ++k) a += G[r * D + k] * U[k * D + c];
        C[r * D + c] = a;
    }
}

// ---------------------------------------------------------------------------
// prep2: EKGU_s = embk_s @ GU_s[0:128]  (50x128). 25 blocks/side.
// ---------------------------------------------------------------------------
__global__ __launch_bounds__(256) void prep2_kernel(
    const float* __restrict__ uek, const float* __restrict__ iek,
    const float* __restrict__ GUu, const float* __restrict__ GUi,
    float* __restrict__ EKGUu, float* __restrict__ EKGUi)
{
    int b = blockIdx.x, t = threadIdx.x;
    int side = b / 25;
    int o = (b % 25) * 256 + t;                     // < 6400
    int r = o >> 7, c = o & 127;
    const float* EK = side ? iek : uek;
    const float* GU = side ? GUi : GUu;
    float* C        = side ? EKGUi : EKGUu;
    float a = 0.f;
    for (int k = 0; k < D; ++k) a += EK[r * D + k] * GU[k * D + c];
    C[r * D + c] = a;
}

// ---------------------------------------------------------------------------
// proj: per 8 nodes, h = x @ W (thr 0..127), eproj = x @ WE (thr 128..177)
// ---------------------------------------------------------------------------
__global__ __launch_bounds__(192) void proj_kernel(
    const float* __restrict__ user, const float* __restrict__ item,
    const float* __restrict__ Wu, const float* __restrict__ Wi,
    const float* __restrict__ WEu, const float* __restrict__ WEi,
    float* __restrict__ h, float* __restrict__ eproj, int NU, int NI)
{
    __shared__ float srowT[D][8];
    int b = blockIdx.x, t = threadIdx.x;
    int nblk_u = NU / 8;
    const float* X; const float* W; const float* WE; int n0, base;
    if (b < nblk_u) { X = user; W = Wu; WE = WEu; n0 = b * 8;            base = 0; }
    else            { X = item; W = Wi; WE = WEi; n0 = (b - nblk_u) * 8; base = NU; }

    if (t < D)
        for (int r = 0; r < 8; ++r) srowT[t][r] = X[(size_t)(n0 + r) * D + t];
    __syncthreads();

    if (t < D + L) {
        const float* wp; int wstride;
        if (t < D) { wp = W + t;        wstride = D; }
        else       { wp = WE + (t - D); wstride = L; }
        float acc[8] = {0, 0, 0, 0, 0, 0, 0, 0};
        for (int k = 0; k < D; ++k) {
            float w  = wp[(size_t)k * wstride];
            float4 a0 = *(const float4*)&srowT[k][0];
            float4 a1 = *(const float4*)&srowT[k][4];
            acc[0] += a0.x * w; acc[1] += a0.y * w; acc[2] += a0.z * w; acc[3] += a0.w * w;
            acc[4] += a1.x * w; acc[5] += a1.y * w; acc[6] += a1.z * w; acc[7] += a1.w * w;
        }
        if (t < D) {
            for (int r = 0; r < 8; ++r) h[(size_t)(base + n0 + r) * D + t] = acc[r];
        } else {
            int l = t - D;
            for (int r = 0; r < 8; ++r) eproj[(size_t)(base + n0 + r) * L + l] = acc[r];
        }
    }
}

// ---------------------------------------------------------------------------
// agg: gather mailbox (bf16 in LDS) + ranks + both attentions.
// writes scat = [hl_mail(128) | hs(128) | beta(50) | 0(14)]  (stride 320)
// LDS ~15 KB -> 10 blocks/CU.
// ---------------------------------------------------------------------------
__global__ __launch_bounds__(128) void agg_kernel(
    const float* __restrict__ h, const float* __restrict__ eproj,
    const int* __restrict__ unbr, const int* __restrict__ untime,
    const int* __restrict__ inbr, const int* __restrict__ intime,
    float* __restrict__ scat, int NU, int NI)
{
    __shared__ unsigned smail[L][65];   // packed 2xbf16; odd stride: all reads <=2-way
    __shared__ float sh[D];
    __shared__ float se[L], se1[L], salpha[L], salpha1[L];
    __shared__ int stime[L], sreorder[L], snbr[L], slast;

    int g = blockIdx.x, t = threadIdx.x;
    const float* mail; const int* nbrp; const int* timp;
    if (g < NU) { mail = h + (size_t)NU * D; nbrp = unbr + (size_t)g * L;        timp = untime + (size_t)g * L; }
    else        { mail = h;                  nbrp = inbr + (size_t)(g - NU) * L; timp = intime + (size_t)(g - NU) * L; }

    sh[t] = h[(size_t)g * D + t];
    if (t < L) { stime[t] = timp[t]; snbr[t] = nbrp[t]; }
    __syncthreads();

    // ranks (stable argsort∘argsort) + first-occurrence argmax
    if (t < L) {
        int ti = stime[t]; int rank = 0; bool firstmax = true;
        for (int j = 0; j < L; ++j) {
            int tj = stime[j];
            rank += (tj < ti) || (tj == ti && j < t);
            firstmax = firstmax && ((tj < ti) || (tj == ti && j >= t));
        }
        sreorder[t] = L - 1 - rank;
        if (firstmax) slast = t;
    }
    // stage mail: float4 gather -> bf16x2 pair, stride-2 u32 writes (2-way, free)
    {
        int q = t >> 5, c4 = (t & 31) * 4;
        #pragma unroll
        for (int i = 0; i < 13; ++i) {
            int l = i * 4 + q;
            if (l < L) {
                float4 v = *(const float4*)&mail[(size_t)snbr[l] * D + c4];
                smail[l][(c4 >> 1)]     = f2bf(v.x) | (f2bf(v.y) << 16);
                smail[l][(c4 >> 1) + 1] = f2bf(v.z) | (f2bf(v.w) << 16);
            }
        }
    }
    __syncthreads();

    // scores: wave0 -> long-term, wave1 -> short-term
    {
        int w = t >> 6, lane = t & 63;
        if (lane < L) {
            if (w == 0) {
                float a = 0.f;
                for (int p = 0; p < D / 2; ++p) {
                    unsigned u = smail[lane][p];
                    float2 s2 = *(const float2*)&sh[2 * p];
                    a += bflo(u) * s2.x + bfhi(u) * s2.y;
                }
                se[lane] = (a + eproj[(size_t)g * L + sreorder[lane]]) * SCALE;
            } else {
                int li = slast;
                float a1 = 0.f;
                for (int p = 0; p < D / 2; ++p) {
                    unsigned u = smail[lane][p];
                    unsigned v = smail[li][p];          // broadcast
                    a1 += bflo(u) * bflo(v) + bfhi(u) * bfhi(v);
                }
                se1[lane] = a1 * SCALE;
            }
        }
    }
    __syncthreads();

    float m = -1e30f, m1 = -1e30f;
    for (int l = 0; l < L; ++l) { m = fmaxf(m, se[l]); m1 = fmaxf(m1, se1[l]); }
    if (t < L) { salpha[t] = expf(se[t] - m); salpha1[t] = expf(se1[t] - m1); }
    __syncthreads();

    float s = 0.f, s1 = 0.f;
    for (int l = 0; l < L; ++l) { s += salpha[l]; s1 += salpha1[l]; }
    float inv = 1.f / s, inv1 = 1.f / s1;

    // weighted sums: thread t owns dim t; extract its bf16 half
    float hl = 0.f, hs = 0.f;
    {
        int p = t >> 1;
        unsigned sh16 = (t & 1) * 16;
        for (int l = 0; l < L; ++l) {
            unsigned u = smail[l][p];
            union { unsigned u; float f; } v; v.u = (u >> sh16) << 16;
            hl += salpha[l]  * v.f;
            hs += salpha1[l] * v.f;
        }
    }
    float* srow = scat + (size_t)g * 320;
    srow[t]     = hl * inv;
    srow[D + t] = hs * inv1;
    if (t < L)       srow[256 + sreorder[t]] = salpha[t] * inv;  // beta (permuted)
    else if (t < 64) srow[256 + t] = 0.f;                        // zero 306..319
}

// ---------------------------------------------------------------------------
// gemm_out: out = tanh( [scat(320) | x(128)] @ B448 )
// B448 rows: 0..255 GU, 256..305 EKGU, 306..319 zero, 320..447 upd[128:256].
// 32 rows x 128 cols per block, 256 threads, 2x8 micro-tile.
// ---------------------------------------------------------------------------
__global__ __launch_bounds__(256) void gemm_out(
    const float* __restrict__ scat,
    const float* __restrict__ user, const float* __restrict__ item,
    const float* __restrict__ GUu, const float* __restrict__ GUi,
    const float* __restrict__ EKGUu, const float* __restrict__ EKGUi,
    const float* __restrict__ upd_u, const float* __restrict__ upd_i,
    float* __restrict__ out, int NU)
{
    __shared__ float AcT[32][34];
    __shared__ float Bc[32][132];
    int t = threadIdx.x;
    int nb = blockIdx.x * 32;
    const float* GU   = (nb < NU) ? GUu   : GUi;
    const float* EKGU = (nb < NU) ? EKGUu : EKGUi;
    const float* upd  = (nb < NU) ? upd_u : upd_i;
    const float* X    = (nb < NU) ? user  : item;
    int xoff = (nb < NU) ? 0 : NU;
    int tx = t & 15, ty = t >> 4;
    float acc[2][8];
    for (int i = 0; i < 2; ++i)
        for (int j = 0; j < 8; ++j) acc[i][j] = 0.f;

    int sr = t >> 3, sj = t & 7;
    for (int kc = 0; kc < 14; ++kc) {
        int K0 = kc * 32;
        {   // A-stage
            int n = nb + sr, k4 = K0 + sj * 4;
            float4 v = (K0 < 320)
                ? *(const float4*)&scat[(size_t)n * 320 + k4]
                : *(const float4*)&X[(size_t)(n - xoff) * D + (k4 - 320)];
            AcT[sj * 4 + 0][sr] = v.x; AcT[sj * 4 + 1][sr] = v.y;
            AcT[sj * 4 + 2][sr] = v.z; AcT[sj * 4 + 3][sr] = v.w;
        }
        {   // B-stage
            int k = K0 + sr, cb = sj * 16;
            for (int q = 0; q < 4; ++q) {
                float4 v;
                if (k < 256)      v = *(const float4*)&GU[(size_t)k * D + cb + q * 4];
                else if (k < 306) v = *(const float4*)&EKGU[(size_t)(k - 256) * D + cb + q * 4];
                else if (k < 320) v = make_float4(0.f, 0.f, 0.f, 0.f);
                else              v = *(const float4*)&upd[(size_t)(k - 192) * D + cb + q * 4];
                *(float4*)&Bc[sr][cb + q * 4] = v;
            }
        }
        __syncthreads();
        for (int kk = 0; kk < 32; ++kk) {
            float2 av = *(const float2*)&AcT[kk][ty * 2];
            float4 b0 = *(const float4*)&Bc[kk][tx * 8];
            float4 b1 = *(const float4*)&Bc[kk][tx * 8 + 4];
            acc[0][0] += av.x * b0.x; acc[0][1] += av.x * b0.y;
            acc[0][2] += av.x * b0.z; acc[0][3] += av.x * b0.w;
            acc[0][4] += av.x * b1.x; acc[0][5] += av.x * b1.y;
            acc[0][6] += av.x * b1.z; acc[0][7] += av.x * b1.w;
            acc[1][0] += av.y * b0.x; acc[1][1] += av.y * b0.y;
            acc[1][2] += av.y * b0.z; acc[1][3] += av.y * b0.w;
            acc[1][4] += av.y * b1.x; acc[1][5] += av.y * b1.y;
            acc[1][6] += av.y * b1.z; acc[1][7] += av.y * b1.w;
        }
        __syncthreads();
    }
    for (int i = 0; i < 2; ++i) {
        size_t n = nb + ty * 2 + i;
        *(float4*)&out[n * D + tx * 8] = make_float4(
            tanhf(acc[i][0]), tanhf(acc[i][1]), tanhf(acc[i][2]), tanhf(acc[i][3]));
        *(float4*)&out[n * D + tx * 8 + 4] = make_float4(
            tanhf(acc[i][4]), tanhf(acc[i][5]), tanhf(acc[i][6]), tanhf(acc[i][7]));
    }
}

// ---------------------------------------------------------------------------
extern "C" void kernel_launch(void* const* d_in, const int* in_sizes, int n_in,
                              void* d_out, int out_size, void* d_ws, size_t ws_size,
                              hipStream_t stream) {
    const float* user   = (const float*)d_in[0];
    const float* item   = (const float*)d_in[1];
    const float* Wu     = (const float*)d_in[2];
    const float* Wi     = (const float*)d_in[3];
    const float* gate_u = (const float*)d_in[4];
    const float* gate_i = (const float*)d_in[5];
    const float* upd_u  = (const float*)d_in[6];
    const float* upd_i  = (const float*)d_in[7];
    const float* uemb   = (const float*)d_in[8];
    const float* uembk  = (const float*)d_in[9];
    const float* iemb   = (const float*)d_in[10];
    const float* iembk  = (const float*)d_in[11];
    const int*   unbr   = (const int*)d_in[12];
    const int*   untime = (const int*)d_in[13];
    const int*   inbr   = (const int*)d_in[14];
    const int*   intime = (const int*)d_in[15];

    int NU = in_sizes[0] / D;
    int NI = in_sizes[1] / D;
    int N  = NU + NI;

    float* h      = (float*)d_ws;                   // N*D
    float* eproj  = h + (size_t)N * D;              // N*L
    float* scat   = eproj + (size_t)N * L;          // N*320
    float* WEu    = scat + (size_t)N * 320;         // D*L
    float* WEi    = WEu + D * L;
    float* GUu    = WEi + D * L;                    // 256*128
    float* GUi    = GUu + 256 * D;
    float* EKGUu  = GUi + 256 * D;                  // 50*128
    float* EKGUi  = EKGUu + L * D;

    prep1_kernel<<<306, 256, 0, stream>>>(Wu, Wi, uemb, iemb, gate_u, gate_i,
                                          upd_u, upd_i, WEu, WEi, GUu, GUi);
    prep2_kernel<<<50, 256, 0, stream>>>(uembk, iembk, GUu, GUi, EKGUu, EKGUi);
    proj_kernel<<<N / 8, 192, 0, stream>>>(user, item, Wu, Wi, WEu, WEi,
                                           h, eproj, NU, NI);
    agg_kernel<<<N, 128, 0, stream>>>(h, eproj, unbr, untime, inbr, intime,
                                      scat, NU, NI);
    gemm_out<<<N / 32, 256, 0, stream>>>(scat, user, item, GUu, GUi,
                                         EKGUu, EKGUi, upd_u, upd_i,
                                         (float*)d_out, NU);
}

// Round 4
// 210.281 us; speedup vs baseline: 1.9465x; 1.1780x over previous
//
#include <hip/hip_runtime.h>
#include <math.h>

#define D 128
#define L 50
#define SCALE 0.08838834764831845f   // 1/sqrt(128)

using bf16x8 = __attribute__((ext_vector_type(8))) short;   // MFMA A/B frag (4 VGPR)
using f32x4  = __attribute__((ext_vector_type(4))) float;   // MFMA C/D frag

// ---- bf16 pack/unpack helpers (RNE) ---------------------------------------
__device__ __forceinline__ unsigned f2bf(float x) {
    union { float f; unsigned u; } v; v.f = x;
    return (v.u + 0x7fffu + ((v.u >> 16) & 1u)) >> 16;
}
__device__ __forceinline__ float bflo(unsigned u) {
    union { unsigned u; float f; } v; v.u = u << 16; return v.f;
}
__device__ __forceinline__ float bfhi(unsigned u) {
    union { unsigned u; float f; } v; v.u = u & 0xffff0000u; return v.f;
}

// ---------------------------------------------------------------------------
// prep1: blocks 0..49   : WE_s = W_s @ emb_s^T (128x50, f32)
//        blocks 50..305 : GU_s = gate_s @ upd_s[0:128] (256x128, f32)
//                         + scatter GU^T as bf16 into B448t cols 0..255
//        blocks 306..561: scatter upd_s[128:256]^T bf16 into B448t cols 320..447
//                         + zero pad cols 306..319
// B448t layout: [n=0..127][k=0..447] bf16, row stride 448.
// ---------------------------------------------------------------------------
__global__ __launch_bounds__(256) void prep1_kernel(
    const float* __restrict__ Wu, const float* __restrict__ Wi,
    const float* __restrict__ ue, const float* __restrict__ ie,
    const float* __restrict__ gu, const float* __restrict__ gi,
    const float* __restrict__ uu, const float* __restrict__ ui,
    float* __restrict__ WEu, float* __restrict__ WEi,
    float* __restrict__ GUu, float* __restrict__ GUi,
    unsigned short* __restrict__ Btu, unsigned short* __restrict__ Bti)
{
    int b = blockIdx.x, t = threadIdx.x;
    if (b < 50) {
        int side = b / 25;
        int o = (b % 25) * 256 + t;                 // < 6400
        int d = o / L, l = o % L;
        const float* W = side ? Wi : Wu;
        const float* E = side ? ie : ue;
        float* C       = side ? WEi : WEu;
        float a = 0.f;
        for (int k = 0; k < D; ++k) a += W[d * D + k] * E[l * D + k];
        C[d * L + l] = a;
    } else if (b < 306) {
        int bb = b - 50;
        int side = bb / 128;
        int o = (bb % 128) * 256 + t;               // < 32768
        int r = o >> 7, c = o & 127;
        const float* G = side ? gi : gu;
        const float* U = side ? ui : uu;
        float* GU      = side ? GUi : GUu;
        unsigned short* Bt = side ? Bti : Btu;
        float a = 0.f;
        for (int k = 0; k < D; ++k) a += G[r * D + k] * U[k * D + c];
        GU[r * D + c] = a;
        Bt[c * 448 + r] = (unsigned short)f2bf(a);
    } else {
        int bb = b - 306;
        int side = bb / 128;
        int o = (bb % 128) * 256 + t;               // < 32768
        int r = o >> 7, c = o & 127;
        const float* U = side ? ui : uu;
        unsigned short* Bt = side ? Bti : Btu;
        Bt[c * 448 + 320 + r] = (unsigned short)f2bf(U[(128 + r) * D + c]);
        if (r < 14) Bt[c * 448 + 306 + r] = 0;
    }
}

// ---------------------------------------------------------------------------
// prep2: EKGU_s = embk_s @ GU_s[0:128]  (50x128) -> bf16 into B448t cols 256..305
// ---------------------------------------------------------------------------
__global__ __launch_bounds__(256) void prep2_kernel(
    const float* __restrict__ uek, const float* __restrict__ iek,
    const float* __restrict__ GUu, const float* __restrict__ GUi,
    unsigned short* __restrict__ Btu, unsigned short* __restrict__ Bti)
{
    int b = blockIdx.x, t = threadIdx.x;
    int side = b / 25;
    int o = (b % 25) * 256 + t;                     // < 6400
    int r = o >> 7, c = o & 127;
    const float* EK = side ? iek : uek;
    const float* GU = side ? GUi : GUu;
    unsigned short* Bt = side ? Bti : Btu;
    float a = 0.f;
    for (int k = 0; k < D; ++k) a += EK[r * D + k] * GU[k * D + c];
    Bt[c * 448 + 256 + r] = (unsigned short)f2bf(a);
}

// ---------------------------------------------------------------------------
// proj: per 8 nodes, h = x @ W (thr 0..127), eproj = x @ WE (thr 128..177),
// plus pack x as bf16 into A-matrix words 160..223 (dims 320..447).
// ---------------------------------------------------------------------------
__global__ __launch_bounds__(192) void proj_kernel(
    const float* __restrict__ user, const float* __restrict__ item,
    const float* __restrict__ Wu, const float* __restrict__ Wi,
    const float* __restrict__ WEu, const float* __restrict__ WEi,
    float* __restrict__ h, float* __restrict__ eproj,
    unsigned* __restrict__ A32, int NU, int NI)
{
    __shared__ float srowT[D][8];
    int b = blockIdx.x, t = threadIdx.x;
    int nblk_u = NU / 8;
    const float* X; const float* W; const float* WE; int n0, base;
    if (b < nblk_u) { X = user; W = Wu; WE = WEu; n0 = b * 8;            base = 0; }
    else            { X = item; W = Wi; WE = WEi; n0 = (b - nblk_u) * 8; base = NU; }

    if (t < D)
        for (int r = 0; r < 8; ++r) srowT[t][r] = X[(size_t)(n0 + r) * D + t];
    __syncthreads();

    if (t < D + L) {
        const float* wp; int wstride;
        if (t < D) { wp = W + t;        wstride = D; }
        else       { wp = WE + (t - D); wstride = L; }
        float acc[8] = {0, 0, 0, 0, 0, 0, 0, 0};
        for (int k = 0; k < D; ++k) {
            float w  = wp[(size_t)k * wstride];
            float4 a0 = *(const float4*)&srowT[k][0];
            float4 a1 = *(const float4*)&srowT[k][4];
            acc[0] += a0.x * w; acc[1] += a0.y * w; acc[2] += a0.z * w; acc[3] += a0.w * w;
            acc[4] += a1.x * w; acc[5] += a1.y * w; acc[6] += a1.z * w; acc[7] += a1.w * w;
        }
        if (t < D) {
            for (int r = 0; r < 8; ++r) h[(size_t)(base + n0 + r) * D + t] = acc[r];
        } else {
            int l = t - D;
            for (int r = 0; r < 8; ++r) eproj[(size_t)(base + n0 + r) * L + l] = acc[r];
        }
    }
    // x -> bf16 into A32 words 160..223
    if (t < 64) {
        for (int r = 0; r < 8; ++r) {
            unsigned lo = f2bf(srowT[2 * t][r]);
            unsigned hi = f2bf(srowT[2 * t + 1][r]);
            A32[(size_t)(base + n0 + r) * 224 + 160 + t] = lo | (hi << 16);
        }
    }
}

// ---------------------------------------------------------------------------
// agg: gather mailbox (bf16 LDS) + ranks + both attentions (shuffle softmax).
// Writes A-matrix words: 0..63 hl (wave0), 64..127 hs (wave1),
// 128..159 zero then beta shorts at 256+reorder (dims 256..305).
// ---------------------------------------------------------------------------
__global__ __launch_bounds__(128) void agg_kernel(
    const float* __restrict__ h, const float* __restrict__ eproj,
    const int* __restrict__ unbr, const int* __restrict__ untime,
    const int* __restrict__ inbr, const int* __restrict__ intime,
    unsigned* __restrict__ A32, int NU, int NI)
{
    __shared__ unsigned smail[L][65];   // packed 2xbf16; odd stride: reads <=2-way
    __shared__ float sh[D];
    __shared__ float salpha[L], salpha1[L];   // normalized alphas
    __shared__ int stime[L], sreorder[L], snbr[L], slast;

    int g = blockIdx.x, t = threadIdx.x;
    int wave = t >> 6, lane = t & 63;
    const float* mail; const int* nbrp; const int* timp;
    if (g < NU) { mail = h + (size_t)NU * D; nbrp = unbr + (size_t)g * L;        timp = untime + (size_t)g * L; }
    else        { mail = h;                  nbrp = inbr + (size_t)(g - NU) * L; timp = intime + (size_t)(g - NU) * L; }

    sh[t] = h[(size_t)g * D + t];
    if (t < L) { stime[t] = timp[t]; snbr[t] = nbrp[t]; }
    __syncthreads();

    // ranks (stable argsort∘argsort) + first-occurrence argmax
    if (t < L) {
        int ti = stime[t]; int rank = 0; bool firstmax = true;
        for (int j = 0; j < L; ++j) {
            int tj = stime[j];
            rank += (tj < ti) || (tj == ti && j < t);
            firstmax = firstmax && ((tj < ti) || (tj == ti && j >= t));
        }
        sreorder[t] = L - 1 - rank;
        if (firstmax) slast = t;
    }
    // stage mail: float4 gather -> bf16x2, stride-2 u32 writes (2-way, free)
    {
        int q = t >> 5, c4 = (t & 31) * 4;
        #pragma unroll
        for (int i = 0; i < 13; ++i) {
            int l = i * 4 + q;
            if (l < L) {
                float4 v = *(const float4*)&mail[(size_t)snbr[l] * D + c4];
                smail[l][(c4 >> 1)]     = f2bf(v.x) | (f2bf(v.y) << 16);
                smail[l][(c4 >> 1) + 1] = f2bf(v.z) | (f2bf(v.w) << 16);
            }
        }
    }
    __syncthreads();

    // scores in-register: wave0 long-term, wave1 short-term
    float sc = -1e30f;
    if (lane < L) {
        if (wave == 0) {
            float a = 0.f;
            for (int p = 0; p < D / 2; ++p) {
                unsigned u = smail[lane][p];
                float2 s2 = *(const float2*)&sh[2 * p];
                a += bflo(u) * s2.x + bfhi(u) * s2.y;
            }
            sc = (a + eproj[(size_t)g * L + sreorder[lane]]) * SCALE;
        } else {
            int li = slast;
            float a1 = 0.f;
            for (int p = 0; p < D / 2; ++p) {
                unsigned u = smail[lane][p];
                unsigned v = smail[li][p];
                a1 += bflo(u) * bflo(v) + bfhi(u) * bfhi(v);
            }
            sc = a1 * SCALE;
        }
    }
    // wave-level softmax (64-lane butterflies)
    float mx = sc;
    for (int off = 32; off; off >>= 1) mx = fmaxf(mx, __shfl_xor(mx, off));
    float ex = (lane < L) ? expf(sc - mx) : 0.f;
    float sm = ex;
    for (int off = 32; off; off >>= 1) sm += __shfl_xor(sm, off);
    float al = ex / sm;                              // normalized
    if (lane < L) { if (wave == 0) salpha[lane] = al; else salpha1[lane] = al; }
    __syncthreads();

    // weighted sums: wave0 -> hl dims pair(2*lane), wave1 -> hs
    {
        const float* alp = wave ? salpha1 : salpha;
        float ax = 0.f, ay = 0.f;
        for (int l = 0; l < L; ++l) {
            unsigned u = smail[l][lane];
            float a = alp[l];
            ax += a * bflo(u);
            ay += a * bfhi(u);
        }
        A32[(size_t)g * 224 + wave * 64 + lane] = f2bf(ax) | (f2bf(ay) << 16);
    }
    // zero beta/pad region words 128..159
    if (t >= 64 && t < 96) A32[(size_t)g * 224 + 128 + (t - 64)] = 0u;
    __syncthreads();
    if (t < L) {
        ((unsigned short*)A32)[(size_t)g * 448 + 256 + sreorder[t]] =
            (unsigned short)f2bf(salpha[t]);
    }
}

// ---------------------------------------------------------------------------
// gemm_out_mfma: out = tanh(A(N x 448 bf16) @ B448t^T(448 x 128 bf16))
// Block: 32 rows x 128 cols, 4 waves; wave w covers cols [w*32, w*32+32).
// MFMA 16x16x32 bf16. LDS rows padded to 20 u32 (80 B) -> conflict-free b128.
// ---------------------------------------------------------------------------
__global__ __launch_bounds__(256) void gemm_out_mfma(
    const unsigned* __restrict__ A32,
    const unsigned* __restrict__ Btu32, const unsigned* __restrict__ Bti32,
    float* __restrict__ out, int NU)
{
    __shared__ __align__(16) unsigned As[32 * 20];    // 32 rows x 16 u32 (+4 pad)
    __shared__ __align__(16) unsigned Bs[128 * 20];   // 128 rows x 16 u32 (+4 pad)
    int t = threadIdx.x;
    int nb = blockIdx.x * 32;
    const unsigned* Bt = (nb < NU) ? Btu32 : Bti32;   // [n][224 u32]
    int wave = t >> 6, lane = t & 63;
    int m16 = lane & 15, quad = lane >> 4;
    int ncol0 = wave * 32;

    f32x4 acc[2][2] = {{{0.f, 0.f, 0.f, 0.f}, {0.f, 0.f, 0.f, 0.f}},
                       {{0.f, 0.f, 0.f, 0.f}, {0.f, 0.f, 0.f, 0.f}}};

    for (int kc = 0; kc < 14; ++kc) {
        // stage A chunk: 32 rows x 16 u32
        if (t < 128) {
            int row = t >> 2, q = t & 3;
            uint4 v = *(const uint4*)&A32[(size_t)(nb + row) * 224 + kc * 16 + q * 4];
            *(uint4*)&As[row * 20 + q * 4] = v;
        }
        // stage B chunk: 128 rows x 16 u32
        #pragma unroll
        for (int i = 0; i < 2; ++i) {
            int idx = t * 2 + i;
            int n = idx >> 2, q = idx & 3;
            uint4 v = *(const uint4*)&Bt[(size_t)n * 224 + kc * 16 + q * 4];
            *(uint4*)&Bs[n * 20 + q * 4] = v;
        }
        __syncthreads();
        bf16x8 a0 = *(const bf16x8*)&As[m16 * 20 + quad * 4];
        bf16x8 a1 = *(const bf16x8*)&As[(16 + m16) * 20 + quad * 4];
        bf16x8 b0 = *(const bf16x8*)&Bs[(ncol0 + m16) * 20 + quad * 4];
        bf16x8 b1 = *(const bf16x8*)&Bs[(ncol0 + 16 + m16) * 20 + quad * 4];
        acc[0][0] = __builtin_amdgcn_mfma_f32_16x16x32_bf16(a0, b0, acc[0][0], 0, 0, 0);
        acc[0][1] = __builtin_amdgcn_mfma_f32_16x16x32_bf16(a0, b1, acc[0][1], 0, 0, 0);
        acc[1][0] = __builtin_amdgcn_mfma_f32_16x16x32_bf16(a1, b0, acc[1][0], 0, 0, 0);
        acc[1][1] = __builtin_amdgcn_mfma_f32_16x16x32_bf16(a1, b1, acc[1][1], 0, 0, 0);
        __syncthreads();
    }
    // epilogue: C/D layout col=lane&15, row=quad*4+reg  (verified m89/m91)
    #pragma unroll
    for (int mi = 0; mi < 2; ++mi)
        #pragma unroll
        for (int ni = 0; ni < 2; ++ni)
            #pragma unroll
            for (int r = 0; r < 4; ++r) {
                int row = nb + mi * 16 + quad * 4 + r;
                int col = ncol0 + ni * 16 + m16;
                out[(size_t)row * D + col] = tanhf(acc[mi][ni][r]);
            }
}

// ---------------------------------------------------------------------------
extern "C" void kernel_launch(void* const* d_in, const int* in_sizes, int n_in,
                              void* d_out, int out_size, void* d_ws, size_t ws_size,
                              hipStream_t stream) {
    const float* user   = (const float*)d_in[0];
    const float* item   = (const float*)d_in[1];
    const float* Wu     = (const float*)d_in[2];
    const float* Wi     = (const float*)d_in[3];
    const float* gate_u = (const float*)d_in[4];
    const float* gate_i = (const float*)d_in[5];
    const float* upd_u  = (const float*)d_in[6];
    const float* upd_i  = (const float*)d_in[7];
    const float* uemb   = (const float*)d_in[8];
    const float* uembk  = (const float*)d_in[9];
    const float* iemb   = (const float*)d_in[10];
    const float* iembk  = (const float*)d_in[11];
    const int*   unbr   = (const int*)d_in[12];
    const int*   untime = (const int*)d_in[13];
    const int*   inbr   = (const int*)d_in[14];
    const int*   intime = (const int*)d_in[15];

    int NU = in_sizes[0] / D;
    int NI = in_sizes[1] / D;
    int N  = NU + NI;

    float* h      = (float*)d_ws;                   // N*128 f32
    float* eproj  = h + (size_t)N * D;              // N*50 f32
    float* WEu    = eproj + (size_t)N * L;          // 6400 f32
    float* WEi    = WEu + D * L;
    float* GUu    = WEi + D * L;                    // 32768 f32 each
    float* GUi    = GUu + 256 * D;
    unsigned* A32   = (unsigned*)(GUi + 256 * D);   // N*224 u32 (bf16 A, stride 448)
    unsigned* Btu32 = A32 + (size_t)N * 224;        // 128*224 u32 each
    unsigned* Bti32 = Btu32 + 128 * 224;

    prep1_kernel<<<562, 256, 0, stream>>>(Wu, Wi, uemb, iemb, gate_u, gate_i,
                                          upd_u, upd_i, WEu, WEi, GUu, GUi,
                                          (unsigned short*)Btu32,
                                          (unsigned short*)Bti32);
    prep2_kernel<<<50, 256, 0, stream>>>(uembk, iembk, GUu, GUi,
                                         (unsigned short*)Btu32,
                                         (unsigned short*)Bti32);
    proj_kernel<<<N / 8, 192, 0, stream>>>(user, item, Wu, Wi, WEu, WEi,
                                           h, eproj, A32, NU, NI);
    agg_kernel<<<N, 128, 0, stream>>>(h, eproj, unbr, untime, inbr, intime,
                                      A32, NU, NI);
    gemm_out_mfma<<<N / 32, 256, 0, stream>>>(A32, Btu32, Bti32,
                                              (float*)d_out, NU);
}

// Round 6
// 192.729 us; speedup vs baseline: 2.1237x; 1.0911x over previous
//
#include <hip/hip_runtime.h>
#include <math.h>

#define D 128
#define L 50
#define SCALE 0.08838834764831845f   // 1/sqrt(128)

using bf16x8 = __attribute__((ext_vector_type(8))) short;   // MFMA A/B frag
using f32x4  = __attribute__((ext_vector_type(4))) float;   // MFMA C/D frag

// ---- bf16 pack/unpack helpers (RNE) ---------------------------------------
__device__ __forceinline__ unsigned f2bf(float x) {
    union { float f; unsigned u; } v; v.f = x;
    return (v.u + 0x7fffu + ((v.u >> 16) & 1u)) >> 16;
}
__device__ __forceinline__ float bflo(unsigned u) {
    union { unsigned u; float f; } v; v.u = u << 16; return v.f;
}
__device__ __forceinline__ float bfhi(unsigned u) {
    union { unsigned u; float f; } v; v.u = u & 0xffff0000u; return v.f;
}

// ---------------------------------------------------------------------------
// prep1 (564 blocks x 256):
//  b 0..49    : WE = W @ emb^T -> bf16 into Bpt rows 128..177   (25/side)
//  b 50..305  : GU = gate @ upd_top (f32) + bf16 into B448t cols 0..255
//               (128/side; 256 rows x 128 cols)
//  b 306..433 : upd_bot^T bf16 into B448t cols 320..447 (64/side; 128 rows!)
//               + zero cols 306..319
//  b 434..561 : W^T bf16 into Bpt rows 0..127                   (64/side)
//  b 562..563 : zero Bpt rows 178..191
// Bpt layout: [c=0..191][k=0..127] bf16 (proj B, transposed)
// B448t layout: [n=0..127][k=0..447] bf16 (gemm_out B, transposed)
// ---------------------------------------------------------------------------
__global__ __launch_bounds__(256) void prep1_kernel(
    const float* __restrict__ Wu, const float* __restrict__ Wi,
    const float* __restrict__ ue, const float* __restrict__ ie,
    const float* __restrict__ gu, const float* __restrict__ gi,
    const float* __restrict__ uu, const float* __restrict__ ui,
    float* __restrict__ GUu, float* __restrict__ GUi,
    unsigned short* __restrict__ Bptu, unsigned short* __restrict__ Bpti,
    unsigned short* __restrict__ Btu, unsigned short* __restrict__ Bti)
{
    int b = blockIdx.x, t = threadIdx.x;
    if (b < 50) {
        int side = b / 25;
        int o = (b % 25) * 256 + t;                 // < 6400
        int d = o / L, l = o % L;
        const float* W = side ? Wi : Wu;
        const float* E = side ? ie : ue;
        unsigned short* Bpt = side ? Bpti : Bptu;
        float a = 0.f;
        for (int k = 0; k < D; ++k) a += W[d * D + k] * E[l * D + k];
        Bpt[(128 + l) * 128 + d] = (unsigned short)f2bf(a);
    } else if (b < 306) {
        int bb = b - 50;
        int side = bb / 128;
        int o = (bb % 128) * 256 + t;               // < 32768
        int r = o >> 7, c = o & 127;                // r 0..255 (GU has 256 rows)
        const float* G = side ? gi : gu;
        const float* U = side ? ui : uu;
        float* GU      = side ? GUi : GUu;
        unsigned short* Bt = side ? Bti : Btu;
        float a = 0.f;
        for (int k = 0; k < D; ++k) a += G[r * D + k] * U[k * D + c];
        GU[r * D + c] = a;
        Bt[c * 448 + r] = (unsigned short)f2bf(a);
    } else if (b < 434) {
        int bb = b - 306;
        int side = bb >> 6;                         // 64 blocks/side
        int o = (bb & 63) * 256 + t;                // < 16384
        int r = o >> 7, c = o & 127;                // r 0..127 (upd_bot: 128 rows)
        const float* U = side ? ui : uu;
        unsigned short* Bt = side ? Bti : Btu;
        Bt[c * 448 + 320 + r] = (unsigned short)f2bf(U[(128 + r) * D + c]);
        if (r < 14) Bt[c * 448 + 306 + r] = 0;
    } else if (b < 562) {
        int bb = b - 434;
        int side = bb >> 6;
        int o = (bb & 63) * 256 + t;                // < 16384
        int k = o >> 7, c = o & 127;
        const float* W = side ? Wi : Wu;
        unsigned short* Bpt = side ? Bpti : Bptu;
        Bpt[c * 128 + k] = (unsigned short)f2bf(W[k * D + c]);
    } else {
        int side = b - 562;
        unsigned short* Bpt = side ? Bpti : Bptu;
        for (int j = 0; j < 7; ++j)
            Bpt[178 * 128 + t * 7 + j] = 0;
    }
}

// ---------------------------------------------------------------------------
// prep2: EKGU = embk @ GU[0:128]  (50x128) -> bf16 into B448t cols 256..305
// ---------------------------------------------------------------------------
__global__ __launch_bounds__(256) void prep2_kernel(
    const float* __restrict__ uek, const float* __restrict__ iek,
    const float* __restrict__ GUu, const float* __restrict__ GUi,
    unsigned short* __restrict__ Btu, unsigned short* __restrict__ Bti)
{
    int b = blockIdx.x, t = threadIdx.x;
    int side = b / 25;
    int o = (b % 25) * 256 + t;                     // < 6400
    int r = o >> 7, c = o & 127;
    const float* EK = side ? iek : uek;
    const float* GU = side ? GUi : GUu;
    unsigned short* Bt = side ? Bti : Btu;
    float a = 0.f;
    for (int k = 0; k < D; ++k) a += EK[r * D + k] * GU[k * D + c];
    Bt[c * 448 + 256 + r] = (unsigned short)f2bf(a);
}

// ---------------------------------------------------------------------------
// proj_mfma: [h(128) | eproj(50) | pad] = X @ Bpt^T, 32 nodes/block.
// h written as packed bf16 (h32, N x 64 u32); eproj f32; x-bf16 -> A32[160..223].
// ---------------------------------------------------------------------------
__global__ __launch_bounds__(256) void proj_mfma(
    const float* __restrict__ Xu, const float* __restrict__ Xi,
    const unsigned* __restrict__ Bptu32, const unsigned* __restrict__ Bpti32,
    unsigned* __restrict__ h32, float* __restrict__ eproj,
    unsigned* __restrict__ A32, int NU)
{
    __shared__ __align__(16) unsigned As[32 * 20];
    __shared__ __align__(16) unsigned Bs[192 * 20];
    int t = threadIdx.x;
    int nb = blockIdx.x * 32;
    const float* X = (nb < NU) ? Xu : Xi;
    int xoff = (nb < NU) ? 0 : NU;
    const unsigned* Bt = (nb < NU) ? Bptu32 : Bpti32;   // [192][64 u32]
    int wave = t >> 6, lane = t & 63;
    int m16 = lane & 15, quad = lane >> 4;

    f32x4 acc[2][3];
    for (int i = 0; i < 2; ++i)
        for (int j = 0; j < 3; ++j) acc[i][j] = (f32x4){0.f, 0.f, 0.f, 0.f};

    for (int kc = 0; kc < 4; ++kc) {
        if (t < 128) {                                  // A stage + x->A32
            int row = t >> 2, q = t & 3;
            int n = nb + row;
            const float* src = &X[(size_t)(n - xoff) * D + kc * 32 + q * 8];
            float4 v0 = *(const float4*)&src[0];
            float4 v1 = *(const float4*)&src[4];
            uint4 pk;
            pk.x = f2bf(v0.x) | (f2bf(v0.y) << 16);
            pk.y = f2bf(v0.z) | (f2bf(v0.w) << 16);
            pk.z = f2bf(v1.x) | (f2bf(v1.y) << 16);
            pk.w = f2bf(v1.z) | (f2bf(v1.w) << 16);
            *(uint4*)&As[row * 20 + q * 4] = pk;
            *(uint4*)&A32[(size_t)n * 224 + 160 + kc * 16 + q * 4] = pk;
        }
        #pragma unroll
        for (int i = 0; i < 3; ++i) {                   // B stage: 768 uint4
            int idx = t * 3 + i;
            int c = idx >> 2, q = idx & 3;
            uint4 v = *(const uint4*)&Bt[(size_t)c * 64 + kc * 16 + q * 4];
            *(uint4*)&Bs[c * 20 + q * 4] = v;
        }
        __syncthreads();
        bf16x8 a0 = *(const bf16x8*)&As[m16 * 20 + quad * 4];
        bf16x8 a1 = *(const bf16x8*)&As[(16 + m16) * 20 + quad * 4];
        #pragma unroll
        for (int ni = 0; ni < 3; ++ni) {
            bf16x8 bb = *(const bf16x8*)&Bs[(wave * 48 + ni * 16 + m16) * 20 + quad * 4];
            acc[0][ni] = __builtin_amdgcn_mfma_f32_16x16x32_bf16(a0, bb, acc[0][ni], 0, 0, 0);
            acc[1][ni] = __builtin_amdgcn_mfma_f32_16x16x32_bf16(a1, bb, acc[1][ni], 0, 0, 0);
        }
        __syncthreads();
    }
    // epilogue: C/D layout col=lane&15, row=quad*4+r
    #pragma unroll
    for (int mi = 0; mi < 2; ++mi)
        #pragma unroll
        for (int ni = 0; ni < 3; ++ni) {
            int col = wave * 48 + ni * 16 + m16;
            #pragma unroll
            for (int r = 0; r < 4; ++r) {
                float me = acc[mi][ni][r];
                float pr = __shfl_xor(me, 1);           // partner col (lane^1)
                int row = nb + mi * 16 + quad * 4 + r;
                if (col < 128) {
                    if (!(lane & 1))
                        h32[(size_t)row * 64 + (col >> 1)] = f2bf(me) | (f2bf(pr) << 16);
                } else if (col < 178) {
                    eproj[(size_t)row * L + (col - 128)] = me;
                }
            }
        }
}

// ---------------------------------------------------------------------------
// agg: 2 nodes per 256-thread block. Mailbox gathered as packed bf16 u32 into
// XOR-swizzled LDS (row stride 64 u32; logical pair p stored at p^(row&31)).
// All LDS access patterns <=2-way. Writes A32 words 0..159 + beta shorts.
// ---------------------------------------------------------------------------
__global__ __launch_bounds__(256) void agg_kernel(
    const unsigned* __restrict__ h32, const float* __restrict__ eproj,
    const int* __restrict__ unbr, const int* __restrict__ untime,
    const int* __restrict__ inbr, const int* __restrict__ intime,
    unsigned* __restrict__ A32, int NU, int NI)
{
    __shared__ unsigned smail[2][L * 64];
    __shared__ unsigned shb[2][64];
    __shared__ float salpha[2][L], salpha1[2][L];
    __shared__ int stime[2][L], sreorder[2][L], snbr[2][L], slast[2];

    int tb = threadIdx.x;
    int sub = tb >> 7;                  // node slot 0/1
    int t = tb & 127;                   // within-node tid
    int g = blockIdx.x * 2 + sub;       // global node
    int wave = t >> 6, lane = t & 63;

    const unsigned* mail; const int* nbrp; const int* timp;
    if (g < NU) { mail = h32 + (size_t)NU * 64; nbrp = unbr + (size_t)g * L;        timp = untime + (size_t)g * L; }
    else        { mail = h32;                   nbrp = inbr + (size_t)(g - NU) * L; timp = intime + (size_t)(g - NU) * L; }

    if (t < 64) shb[sub][t] = h32[(size_t)g * 64 + t];
    if (t < L) { stime[sub][t] = timp[t]; snbr[sub][t] = nbrp[t]; }
    __syncthreads();

    // ranks (stable argsort∘argsort) + first-occurrence argmax
    if (t < L) {
        int ti = stime[sub][t]; int rank = 0; bool firstmax = true;
        for (int j = 0; j < L; ++j) {
            int tj = stime[sub][j];
            rank += (tj < ti) || (tj == ti && j < t);
            firstmax = firstmax && ((tj < ti) || (tj == ti && j >= t));
        }
        sreorder[sub][t] = L - 1 - rank;
        if (firstmax) slast[sub] = t;
    }
    // stage mail: uint2 global copy -> swizzled LDS (pure copy, no convert)
    {
        int q = t >> 5, p = t & 31;     // row group, logical pair
        #pragma unroll
        for (int i = 0; i < 13; ++i) {
            int l = i * 4 + q;
            if (l < L) {
                uint2 v = *(const uint2*)&mail[(size_t)snbr[sub][l] * 64 + p * 2];
                *(uint2*)&smail[sub][l * 64 + 2 * (p ^ (l & 31))] = v;
            }
        }
    }
    __syncthreads();

    // scores: wave0 long-term, wave1 short-term (uint2 swizzled reads)
    float sc = -1e30f;
    if (lane < L) {
        int xr = lane & 31;
        const unsigned* mrow = &smail[sub][lane * 64];
        if (wave == 0) {
            float a = 0.f;
            for (int p = 0; p < 32; ++p) {
                uint2 mv = *(const uint2*)&mrow[2 * (p ^ xr)];
                uint2 sv = *(const uint2*)&shb[sub][2 * p];
                a += bflo(mv.x) * bflo(sv.x) + bfhi(mv.x) * bfhi(sv.x)
                   + bflo(mv.y) * bflo(sv.y) + bfhi(mv.y) * bfhi(sv.y);
            }
            sc = (a + eproj[(size_t)g * L + sreorder[sub][lane]]) * SCALE;
        } else {
            int li = slast[sub], xl = li & 31;
            const unsigned* lrow = &smail[sub][li * 64];
            float a1 = 0.f;
            for (int p = 0; p < 32; ++p) {
                uint2 mv = *(const uint2*)&mrow[2 * (p ^ xr)];
                uint2 lv = *(const uint2*)&lrow[2 * (p ^ xl)];
                a1 += bflo(mv.x) * bflo(lv.x) + bfhi(mv.x) * bfhi(lv.x)
                    + bflo(mv.y) * bflo(lv.y) + bfhi(mv.y) * bfhi(lv.y);
            }
            sc = a1 * SCALE;
        }
    }
    // wave-level softmax
    float mx = sc;
    for (int off = 32; off; off >>= 1) mx = fmaxf(mx, __shfl_xor(mx, off));
    float ex = (lane < L) ? expf(sc - mx) : 0.f;
    float sm = ex;
    for (int off = 32; off; off >>= 1) sm += __shfl_xor(sm, off);
    float al = ex / sm;
    if (lane < L) { if (wave == 0) salpha[sub][lane] = al; else salpha1[sub][lane] = al; }
    __syncthreads();

    // weighted sums: wave0 -> hl word lane, wave1 -> hs word lane
    {
        const float* alp = wave ? salpha1[sub] : salpha[sub];
        int pr = lane >> 1, bit = lane & 1;
        float ax = 0.f, ay = 0.f;
        for (int l = 0; l < L; ++l) {
            unsigned u = smail[sub][l * 64 + 2 * (pr ^ (l & 31)) + bit];
            float a = alp[l];
            ax += a * bflo(u);
            ay += a * bfhi(u);
        }
        A32[(size_t)g * 224 + wave * 64 + lane] = f2bf(ax) | (f2bf(ay) << 16);
    }
    if (t >= 64 && t < 96) A32[(size_t)g * 224 + 128 + (t - 64)] = 0u;
    __syncthreads();
    if (t < L) {
        ((unsigned short*)A32)[(size_t)g * 448 + 256 + sreorder[sub][t]] =
            (unsigned short)f2bf(salpha[sub][t]);
    }
}

// ---------------------------------------------------------------------------
// gemm_out_mfma: out = tanh(A(N x 448 bf16) @ B448t^T)
// ---------------------------------------------------------------------------
__global__ __launch_bounds__(256) void gemm_out_mfma(
    const unsigned* __restrict__ A32,
    const unsigned* __restrict__ Btu32, const unsigned* __restrict__ Bti32,
    float* __restrict__ out, int NU)
{
    __shared__ __align__(16) unsigned As[32 * 20];
    __shared__ __align__(16) unsigned Bs[128 * 20];
    int t = threadIdx.x;
    int nb = blockIdx.x * 32;
    const unsigned* Bt = (nb < NU) ? Btu32 : Bti32;
    int wave = t >> 6, lane = t & 63;
    int m16 = lane & 15, quad = lane >> 4;
    int ncol0 = wave * 32;

    f32x4 acc[2][2] = {{{0.f, 0.f, 0.f, 0.f}, {0.f, 0.f, 0.f, 0.f}},
                       {{0.f, 0.f, 0.f, 0.f}, {0.f, 0.f, 0.f, 0.f}}};

    for (int kc = 0; kc < 14; ++kc) {
        if (t < 128) {
            int row = t >> 2, q = t & 3;
            uint4 v = *(const uint4*)&A32[(size_t)(nb + row) * 224 + kc * 16 + q * 4];
            *(uint4*)&As[row * 20 + q * 4] = v;
        }
        #pragma unroll
        for (int i = 0; i < 2; ++i) {
            int idx = t * 2 + i;
            int n = idx >> 2, q = idx & 3;
            uint4 v = *(const uint4*)&Bt[(size_t)n * 224 + kc * 16 + q * 4];
            *(uint4*)&Bs[n * 20 + q * 4] = v;
        }
        __syncthreads();
        bf16x8 a0 = *(const bf16x8*)&As[m16 * 20 + quad * 4];
        bf16x8 a1 = *(const bf16x8*)&As[(16 + m16) * 20 + quad * 4];
        bf16x8 b0 = *(const bf16x8*)&Bs[(ncol0 + m16) * 20 + quad * 4];
        bf16x8 b1 = *(const bf16x8*)&Bs[(ncol0 + 16 + m16) * 20 + quad * 4];
        acc[0][0] = __builtin_amdgcn_mfma_f32_16x16x32_bf16(a0, b0, acc[0][0], 0, 0, 0);
        acc[0][1] = __builtin_amdgcn_mfma_f32_16x16x32_bf16(a0, b1, acc[0][1], 0, 0, 0);
        acc[1][0] = __builtin_amdgcn_mfma_f32_16x16x32_bf16(a1, b0, acc[1][0], 0, 0, 0);
        acc[1][1] = __builtin_amdgcn_mfma_f32_16x16x32_bf16(a1, b1, acc[1][1], 0, 0, 0);
        __syncthreads();
    }
    #pragma unroll
    for (int mi = 0; mi < 2; ++mi)
        #pragma unroll
        for (int ni = 0; ni < 2; ++ni)
            #pragma unroll
            for (int r = 0; r < 4; ++r) {
                int row = nb + mi * 16 + quad * 4 + r;
                int col = ncol0 + ni * 16 + m16;
                out[(size_t)row * D + col] = tanhf(acc[mi][ni][r]);
            }
}

// ---------------------------------------------------------------------------
extern "C" void kernel_launch(void* const* d_in, const int* in_sizes, int n_in,
                              void* d_out, int out_size, void* d_ws, size_t ws_size,
                              hipStream_t stream) {
    const float* user   = (const float*)d_in[0];
    const float* item   = (const float*)d_in[1];
    const float* Wu     = (const float*)d_in[2];
    const float* Wi     = (const float*)d_in[3];
    const float* gate_u = (const float*)d_in[4];
    const float* gate_i = (const float*)d_in[5];
    const float* upd_u  = (const float*)d_in[6];
    const float* upd_i  = (const float*)d_in[7];
    const float* uemb   = (const float*)d_in[8];
    const float* uembk  = (const float*)d_in[9];
    const float* iemb   = (const float*)d_in[10];
    const float* iembk  = (const float*)d_in[11];
    const int*   unbr   = (const int*)d_in[12];
    const int*   untime = (const int*)d_in[13];
    const int*   inbr   = (const int*)d_in[14];
    const int*   intime = (const int*)d_in[15];

    int NU = in_sizes[0] / D;
    int NI = in_sizes[1] / D;
    int N  = NU + NI;

    float* eproj  = (float*)d_ws;                   // N*50 f32
    float* GUu    = eproj + (size_t)N * L;          // 32768 f32 each
    float* GUi    = GUu + 256 * D;
    unsigned* h32   = (unsigned*)(GUi + 256 * D);   // N*64 u32 (bf16 h)
    unsigned* A32   = h32 + (size_t)N * 64;         // N*224 u32 (bf16 A)
    unsigned* Btu32 = A32 + (size_t)N * 224;        // 128*224 u32 each
    unsigned* Bti32 = Btu32 + 128 * 224;
    unsigned* Bptu32 = Bti32 + 128 * 224;           // 192*64 u32 each
    unsigned* Bpti32 = Bptu32 + 192 * 64;

    prep1_kernel<<<564, 256, 0, stream>>>(Wu, Wi, uemb, iemb, gate_u, gate_i,
                                          upd_u, upd_i, GUu, GUi,
                                          (unsigned short*)Bptu32,
                                          (unsigned short*)Bpti32,
                                          (unsigned short*)Btu32,
                                          (unsigned short*)Bti32);
    prep2_kernel<<<50, 256, 0, stream>>>(uembk, iembk, GUu, GUi,
                                         (unsigned short*)Btu32,
                                         (unsigned short*)Bti32);
    proj_mfma<<<N / 32, 256, 0, stream>>>(user, item, Bptu32, Bpti32,
                                          h32, eproj, A32, NU);
    agg_kernel<<<N / 2, 256, 0, stream>>>(h32, eproj, unbr, untime, inbr,
                                          intime, A32, NU, NI);
    gemm_out_mfma<<<N / 32, 256, 0, stream>>>(A32, Btu32, Bti32,
                                              (float*)d_out, NU);
}

// Round 7
// 173.654 us; speedup vs baseline: 2.3570x; 1.1098x over previous
//
#include <hip/hip_runtime.h>
#include <math.h>

#define D 128
#define L 50
#define SCALE 0.08838834764831845f   // 1/sqrt(128)

using bf16x8 = __attribute__((ext_vector_type(8))) short;   // MFMA A/B frag
using f32x4  = __attribute__((ext_vector_type(4))) float;   // MFMA C/D frag

union FragU { bf16x8 f; uint2 u2[2]; };

// ---- bf16 pack/unpack helpers (RNE) ---------------------------------------
__device__ __forceinline__ unsigned f2bf(float x) {
    union { float f; unsigned u; } v; v.f = x;
    return (v.u + 0x7fffu + ((v.u >> 16) & 1u)) >> 16;
}
__device__ __forceinline__ float bflo(unsigned u) {
    union { unsigned u; float f; } v; v.u = u << 16; return v.f;
}
__device__ __forceinline__ float bfhi(unsigned u) {
    union { unsigned u; float f; } v; v.u = u & 0xffff0000u; return v.f;
}

// ---------------------------------------------------------------------------
// prep_all (614 blocks x 256):
//  b 0..49    : WE = W @ emb^T -> bf16 into Bpt rows 128..177   (25/side)
//  b 50..305  : GU = gate @ upd_top -> bf16 into B448t cols 0..255 (128/side)
//  b 306..433 : upd_bot^T bf16 into B448t cols 320..447 (64/side)
//               + zero cols 306..319
//  b 434..561 : W^T bf16 into Bpt rows 0..127                   (64/side)
//  b 562..563 : zero Bpt rows 178..191
//  b 564..613 : EKGU = (embk @ gate_top) @ upd_top, 2 rows/block (25/side)
//               -> bf16 into B448t cols 256..305
// ---------------------------------------------------------------------------
__global__ __launch_bounds__(256) void prep_all_kernel(
    const float* __restrict__ Wu, const float* __restrict__ Wi,
    const float* __restrict__ ue, const float* __restrict__ ie,
    const float* __restrict__ gu, const float* __restrict__ gi,
    const float* __restrict__ uu, const float* __restrict__ ui,
    const float* __restrict__ uek, const float* __restrict__ iek,
    unsigned short* __restrict__ Bptu, unsigned short* __restrict__ Bpti,
    unsigned short* __restrict__ Btu, unsigned short* __restrict__ Bti)
{
    __shared__ float T[2][128];                    // only used by EKGU blocks
    int b = blockIdx.x, t = threadIdx.x;
    if (b < 50) {
        int side = b / 25;
        int o = (b % 25) * 256 + t;                 // < 6400
        int d = o / L, l = o % L;
        const float* W = side ? Wi : Wu;
        const float* E = side ? ie : ue;
        unsigned short* Bpt = side ? Bpti : Bptu;
        float a = 0.f;
        for (int k = 0; k < D; ++k) a += W[d * D + k] * E[l * D + k];
        Bpt[(128 + l) * 128 + d] = (unsigned short)f2bf(a);
    } else if (b < 306) {
        int bb = b - 50;
        int side = bb / 128;
        int o = (bb % 128) * 256 + t;               // < 32768
        int r = o >> 7, c = o & 127;                // r 0..255 (GU: 256 rows)
        const float* G = side ? gi : gu;
        const float* U = side ? ui : uu;
        unsigned short* Bt = side ? Bti : Btu;
        float a = 0.f;
        for (int k = 0; k < D; ++k) a += G[r * D + k] * U[k * D + c];
        Bt[c * 448 + r] = (unsigned short)f2bf(a);
    } else if (b < 434) {
        int bb = b - 306;
        int side = bb >> 6;                         // 64 blocks/side
        int o = (bb & 63) * 256 + t;                // < 16384
        int r = o >> 7, c = o & 127;                // r 0..127 (upd_bot)
        const float* U = side ? ui : uu;
        unsigned short* Bt = side ? Bti : Btu;
        Bt[c * 448 + 320 + r] = (unsigned short)f2bf(U[(128 + r) * D + c]);
        if (r < 14) Bt[c * 448 + 306 + r] = 0;
    } else if (b < 562) {
        int bb = b - 434;
        int side = bb >> 6;
        int o = (bb & 63) * 256 + t;                // < 16384
        int k = o >> 7, c = o & 127;
        const float* W = side ? Wi : Wu;
        unsigned short* Bpt = side ? Bpti : Bptu;
        Bpt[c * 128 + k] = (unsigned short)f2bf(W[k * D + c]);
    } else if (b < 564) {
        int side = b - 562;
        unsigned short* Bpt = side ? Bpti : Bptu;
        for (int j = 0; j < 7; ++j)
            Bpt[178 * 128 + t * 7 + j] = 0;
    } else {
        int bb = b - 564;
        int side = bb / 25;
        int ro = (bb % 25) * 2;                     // 2 embk rows per block
        const float* EK = side ? iek : uek;
        const float* G  = side ? gi : gu;
        const float* U  = side ? ui : uu;
        unsigned short* Bt = side ? Bti : Btu;
        int r = t >> 7, c = t & 127;
        float a = 0.f;
        for (int k = 0; k < D; ++k) a += EK[(ro + r) * D + k] * G[k * D + c];
        T[r][c] = a;
        __syncthreads();
        float e = 0.f;
        for (int j = 0; j < D; ++j) e += T[r][j] * U[j * D + c];
        Bt[c * 448 + 256 + ro + r] = (unsigned short)f2bf(e);
    }
}

// ---------------------------------------------------------------------------
// proj_mfma: [h(128) | eproj(50) | pad] = X @ Bpt^T, 32 nodes/block.
// h written as packed bf16 (h32, N x 64 u32); eproj f32; x-bf16 -> A32[160..223].
// ---------------------------------------------------------------------------
__global__ __launch_bounds__(256) void proj_mfma(
    const float* __restrict__ Xu, const float* __restrict__ Xi,
    const unsigned* __restrict__ Bptu32, const unsigned* __restrict__ Bpti32,
    unsigned* __restrict__ h32, float* __restrict__ eproj,
    unsigned* __restrict__ A32, int NU)
{
    __shared__ __align__(16) unsigned As[32 * 20];
    __shared__ __align__(16) unsigned Bs[192 * 20];
    int t = threadIdx.x;
    int nb = blockIdx.x * 32;
    const float* X = (nb < NU) ? Xu : Xi;
    int xoff = (nb < NU) ? 0 : NU;
    const unsigned* Bt = (nb < NU) ? Bptu32 : Bpti32;   // [192][64 u32]
    int wave = t >> 6, lane = t & 63;
    int m16 = lane & 15, quad = lane >> 4;

    f32x4 acc[2][3];
    for (int i = 0; i < 2; ++i)
        for (int j = 0; j < 3; ++j) acc[i][j] = (f32x4){0.f, 0.f, 0.f, 0.f};

    for (int kc = 0; kc < 4; ++kc) {
        if (t < 128) {                                  // A stage + x->A32
            int row = t >> 2, q = t & 3;
            int n = nb + row;
            const float* src = &X[(size_t)(n - xoff) * D + kc * 32 + q * 8];
            float4 v0 = *(const float4*)&src[0];
            float4 v1 = *(const float4*)&src[4];
            uint4 pk;
            pk.x = f2bf(v0.x) | (f2bf(v0.y) << 16);
            pk.y = f2bf(v0.z) | (f2bf(v0.w) << 16);
            pk.z = f2bf(v1.x) | (f2bf(v1.y) << 16);
            pk.w = f2bf(v1.z) | (f2bf(v1.w) << 16);
            *(uint4*)&As[row * 20 + q * 4] = pk;
            *(uint4*)&A32[(size_t)n * 224 + 160 + kc * 16 + q * 4] = pk;
        }
        #pragma unroll
        for (int i = 0; i < 3; ++i) {                   // B stage: 768 uint4
            int idx = t * 3 + i;
            int c = idx >> 2, q = idx & 3;
            uint4 v = *(const uint4*)&Bt[(size_t)c * 64 + kc * 16 + q * 4];
            *(uint4*)&Bs[c * 20 + q * 4] = v;
        }
        __syncthreads();
        bf16x8 a0 = *(const bf16x8*)&As[m16 * 20 + quad * 4];
        bf16x8 a1 = *(const bf16x8*)&As[(16 + m16) * 20 + quad * 4];
        #pragma unroll
        for (int ni = 0; ni < 3; ++ni) {
            bf16x8 bb = *(const bf16x8*)&Bs[(wave * 48 + ni * 16 + m16) * 20 + quad * 4];
            acc[0][ni] = __builtin_amdgcn_mfma_f32_16x16x32_bf16(a0, bb, acc[0][ni], 0, 0, 0);
            acc[1][ni] = __builtin_amdgcn_mfma_f32_16x16x32_bf16(a1, bb, acc[1][ni], 0, 0, 0);
        }
        __syncthreads();
    }
    // epilogue: C/D layout col=lane&15, row=quad*4+r
    #pragma unroll
    for (int mi = 0; mi < 2; ++mi)
        #pragma unroll
        for (int ni = 0; ni < 3; ++ni) {
            int col = wave * 48 + ni * 16 + m16;
            #pragma unroll
            for (int r = 0; r < 4; ++r) {
                float me = acc[mi][ni][r];
                float pr = __shfl_xor(me, 1);           // partner col (lane^1)
                int row = nb + mi * 16 + quad * 4 + r;
                if (col < 128) {
                    if (!(lane & 1))
                        h32[(size_t)row * 64 + (col >> 1)] = f2bf(me) | (f2bf(pr) << 16);
                } else if (col < 178) {
                    eproj[(size_t)row * L + (col - 128)] = me;
                }
            }
        }
}

// ---------------------------------------------------------------------------
// agg: 2 nodes per 256-thread block. Mail in LDS as packed bf16, row stride
// 66 u32 (all patterns <=2-way). Scores via MFMA: S(50x2) = Mail @ [h;last]^T.
// Writes A32 words 0..159 + beta shorts.
// ---------------------------------------------------------------------------
__global__ __launch_bounds__(256) void agg_kernel(
    const unsigned* __restrict__ h32, const float* __restrict__ eproj,
    const int* __restrict__ unbr, const int* __restrict__ untime,
    const int* __restrict__ inbr, const int* __restrict__ intime,
    unsigned* __restrict__ A32, int NU, int NI)
{
    __shared__ unsigned smail[2][L * 66];     // bf16x2, stride 66 u32
    __shared__ unsigned shb[2][64];           // h packed bf16
    __shared__ float se2[2][2][64];           // [long/short][slot]
    __shared__ float salpha[2][L], salpha1[2][L];
    __shared__ int stime[2][L], sreorder[2][L], snbr[2][L], slast[2];

    int tb = threadIdx.x;
    int sub = tb >> 7;                  // node slot 0/1
    int t = tb & 127;                   // within-node tid
    int g = blockIdx.x * 2 + sub;       // global node
    int wave = t >> 6, lane = t & 63;
    int m16 = lane & 15, quad = lane >> 4;

    const unsigned* mail; const int* nbrp; const int* timp;
    if (g < NU) { mail = h32 + (size_t)NU * 64; nbrp = unbr + (size_t)g * L;        timp = untime + (size_t)g * L; }
    else        { mail = h32;                   nbrp = inbr + (size_t)(g - NU) * L; timp = intime + (size_t)(g - NU) * L; }

    if (t < 64) shb[sub][t] = h32[(size_t)g * 64 + t];
    if (t < L) { stime[sub][t] = timp[t]; snbr[sub][t] = nbrp[t]; }
    __syncthreads();

    // ranks (stable argsort∘argsort) + first-occurrence argmax
    if (t < L) {
        int ti = stime[sub][t]; int rank = 0; bool firstmax = true;
        for (int j = 0; j < L; ++j) {
            int tj = stime[sub][j];
            rank += (tj < ti) || (tj == ti && j < t);
            firstmax = firstmax && ((tj < ti) || (tj == ti && j >= t));
        }
        sreorder[sub][t] = L - 1 - rank;
        if (firstmax) slast[sub] = t;
    }
    // stage mail: uint2 global copy -> LDS stride 66 (no convert)
    {
        int q = t >> 5, p = t & 31;     // row group, pair index
        #pragma unroll
        for (int i = 0; i < 13; ++i) {
            int l = i * 4 + q;
            if (l < L) {
                uint2 v = *(const uint2*)&mail[(size_t)snbr[sub][l] * 64 + p * 2];
                *(uint2*)&smail[sub][l * 66 + 2 * p] = v;
            }
        }
    }
    __syncthreads();

    // scores via MFMA: D(16x16) per m-tile; col0 = mail.h (long), col1 = mail.last
    {
        const unsigned* bptr = (m16 == 1) ? &smail[sub][slast[sub] * 66]
                                          : &shb[sub][0];
        int s0 = wave * 32 + m16;  if (s0 > 49) s0 = 49;
        int s1 = wave * 32 + 16 + m16;  if (s1 > 49) s1 = 49;
        const unsigned* a0p = &smail[sub][s0 * 66];
        const unsigned* a1p = &smail[sub][s1 * 66];
        f32x4 d0 = {0.f, 0.f, 0.f, 0.f}, d1 = {0.f, 0.f, 0.f, 0.f};
        #pragma unroll
        for (int kc = 0; kc < 4; ++kc) {
            int off = kc * 16 + quad * 4;
            FragU bf_, af0, af1;
            bf_.u2[0] = *(const uint2*)&bptr[off];
            bf_.u2[1] = *(const uint2*)&bptr[off + 2];
            af0.u2[0] = *(const uint2*)&a0p[off];
            af0.u2[1] = *(const uint2*)&a0p[off + 2];
            af1.u2[0] = *(const uint2*)&a1p[off];
            af1.u2[1] = *(const uint2*)&a1p[off + 2];
            d0 = __builtin_amdgcn_mfma_f32_16x16x32_bf16(af0.f, bf_.f, d0, 0, 0, 0);
            d1 = __builtin_amdgcn_mfma_f32_16x16x32_bf16(af1.f, bf_.f, d1, 0, 0, 0);
        }
        if (m16 < 2) {                   // redistribute: row=quad*4+r, col=m16
            #pragma unroll
            for (int r = 0; r < 4; ++r) {
                se2[sub][m16][wave * 32 + quad * 4 + r]      = d0[r];
                se2[sub][m16][wave * 32 + 16 + quad * 4 + r] = d1[r];
            }
        }
    }
    __syncthreads();

    // softmax: wave0 long (+eproj), wave1 short
    float sc = -1e30f;
    if (lane < L) {
        sc = (wave == 0)
           ? (se2[sub][0][lane] + eproj[(size_t)g * L + sreorder[sub][lane]]) * SCALE
           : se2[sub][1][lane] * SCALE;
    }
    float mx = sc;
    for (int off = 32; off; off >>= 1) mx = fmaxf(mx, __shfl_xor(mx, off));
    float ex = (lane < L) ? expf(sc - mx) : 0.f;
    float sm = ex;
    for (int off = 32; off; off >>= 1) sm += __shfl_xor(sm, off);
    float al = ex / sm;
    if (lane < L) { if (wave == 0) salpha[sub][lane] = al; else salpha1[sub][lane] = al; }
    __syncthreads();

    // weighted sums: wave0 -> hl word lane, wave1 -> hs word lane (linear addr)
    {
        const float* alp = wave ? salpha1[sub] : salpha[sub];
        const unsigned* base = &smail[sub][lane];
        float ax = 0.f, ay = 0.f;
        for (int l = 0; l < L; ++l) {
            unsigned u = base[l * 66];
            float a = alp[l];
            ax += a * bflo(u);
            ay += a * bfhi(u);
        }
        A32[(size_t)g * 224 + wave * 64 + lane] = f2bf(ax) | (f2bf(ay) << 16);
    }
    if (t >= 64 && t < 96) A32[(size_t)g * 224 + 128 + (t - 64)] = 0u;
    __syncthreads();
    if (t < L) {
        ((unsigned short*)A32)[(size_t)g * 448 + 256 + sreorder[sub][t]] =
            (unsigned short)f2bf(salpha[sub][t]);
    }
}

// ---------------------------------------------------------------------------
// gemm_out_mfma: out = tanh(A(N x 448 bf16) @ B448t^T)
// ---------------------------------------------------------------------------
__global__ __launch_bounds__(256) void gemm_out_mfma(
    const unsigned* __restrict__ A32,
    const unsigned* __restrict__ Btu32, const unsigned* __restrict__ Bti32,
    float* __restrict__ out, int NU)
{
    __shared__ __align__(16) unsigned As[32 * 20];
    __shared__ __align__(16) unsigned Bs[128 * 20];
    int t = threadIdx.x;
    int nb = blockIdx.x * 32;
    const unsigned* Bt = (nb < NU) ? Btu32 : Bti32;
    int wave = t >> 6, lane = t & 63;
    int m16 = lane & 15, quad = lane >> 4;
    int ncol0 = wave * 32;

    f32x4 acc[2][2] = {{{0.f, 0.f, 0.f, 0.f}, {0.f, 0.f, 0.f, 0.f}},
                       {{0.f, 0.f, 0.f, 0.f}, {0.f, 0.f, 0.f, 0.f}}};

    for (int kc = 0; kc < 14; ++kc) {
        if (t < 128) {
            int row = t >> 2, q = t & 3;
            uint4 v = *(const uint4*)&A32[(size_t)(nb + row) * 224 + kc * 16 + q * 4];
            *(uint4*)&As[row * 20 + q * 4] = v;
        }
        #pragma unroll
        for (int i = 0; i < 2; ++i) {
            int idx = t * 2 + i;
            int n = idx >> 2, q = idx & 3;
            uint4 v = *(const uint4*)&Bt[(size_t)n * 224 + kc * 16 + q * 4];
            *(uint4*)&Bs[n * 20 + q * 4] = v;
        }
        __syncthreads();
        bf16x8 a0 = *(const bf16x8*)&As[m16 * 20 + quad * 4];
        bf16x8 a1 = *(const bf16x8*)&As[(16 + m16) * 20 + quad * 4];
        bf16x8 b0 = *(const bf16x8*)&Bs[(ncol0 + m16) * 20 + quad * 4];
        bf16x8 b1 = *(const bf16x8*)&Bs[(ncol0 + 16 + m16) * 20 + quad * 4];
        acc[0][0] = __builtin_amdgcn_mfma_f32_16x16x32_bf16(a0, b0, acc[0][0], 0, 0, 0);
        acc[0][1] = __builtin_amdgcn_mfma_f32_16x16x32_bf16(a0, b1, acc[0][1], 0, 0, 0);
        acc[1][0] = __builtin_amdgcn_mfma_f32_16x16x32_bf16(a1, b0, acc[1][0], 0, 0, 0);
        acc[1][1] = __builtin_amdgcn_mfma_f32_16x16x32_bf16(a1, b1, acc[1][1], 0, 0, 0);
        __syncthreads();
    }
    #pragma unroll
    for (int mi = 0; mi < 2; ++mi)
        #pragma unroll
        for (int ni = 0; ni < 2; ++ni)
            #pragma unroll
            for (int r = 0; r < 4; ++r) {
                int row = nb + mi * 16 + quad * 4 + r;
                int col = ncol0 + ni * 16 + m16;
                out[(size_t)row * D + col] = tanhf(acc[mi][ni][r]);
            }
}

// ---------------------------------------------------------------------------
extern "C" void kernel_launch(void* const* d_in, const int* in_sizes, int n_in,
                              void* d_out, int out_size, void* d_ws, size_t ws_size,
                              hipStream_t stream) {
    const float* user   = (const float*)d_in[0];
    const float* item   = (const float*)d_in[1];
    const float* Wu     = (const float*)d_in[2];
    const float* Wi     = (const float*)d_in[3];
    const float* gate_u = (const float*)d_in[4];
    const float* gate_i = (const float*)d_in[5];
    const float* upd_u  = (const float*)d_in[6];
    const float* upd_i  = (const float*)d_in[7];
    const float* uemb   = (const float*)d_in[8];
    const float* uembk  = (const float*)d_in[9];
    const float* iemb   = (const float*)d_in[10];
    const float* iembk  = (const float*)d_in[11];
    const int*   unbr   = (const int*)d_in[12];
    const int*   untime = (const int*)d_in[13];
    const int*   inbr   = (const int*)d_in[14];
    const int*   intime = (const int*)d_in[15];

    int NU = in_sizes[0] / D;
    int NI = in_sizes[1] / D;
    int N  = NU + NI;

    float* eproj  = (float*)d_ws;                   // N*50 f32
    unsigned* h32   = (unsigned*)(eproj + (size_t)N * L);  // N*64 u32
    unsigned* A32   = h32 + (size_t)N * 64;         // N*224 u32 (bf16 A)
    unsigned* Btu32 = A32 + (size_t)N * 224;        // 128*224 u32 each
    unsigned* Bti32 = Btu32 + 128 * 224;
    unsigned* Bptu32 = Bti32 + 128 * 224;           // 192*64 u32 each
    unsigned* Bpti32 = Bptu32 + 192 * 64;

    prep_all_kernel<<<614, 256, 0, stream>>>(Wu, Wi, uemb, iemb, gate_u, gate_i,
                                             upd_u, upd_i, uembk, iembk,
                                             (unsigned short*)Bptu32,
                                             (unsigned short*)Bpti32,
                                             (unsigned short*)Btu32,
                                             (unsigned short*)Bti32);
    proj_mfma<<<N / 32, 256, 0, stream>>>(user, item, Bptu32, Bpti32,
                                          h32, eproj, A32, NU);
    agg_kernel<<<N / 2, 256, 0, stream>>>(h32, eproj, unbr, untime, inbr,
                                          intime, A32, NU, NI);
    gemm_out_mfma<<<N / 32, 256, 0, stream>>>(A32, Btu32, Bti32,
                                              (float*)d_out, NU);
}

// Round 8
// 172.106 us; speedup vs baseline: 2.3782x; 1.0090x over previous
//
#include <hip/hip_runtime.h>
#include <math.h>

#define D 128
#define L 50
#define SCALE 0.08838834764831845f   // 1/sqrt(128)

using bf16x8 = __attribute__((ext_vector_type(8))) short;   // MFMA A/B frag
using f32x4  = __attribute__((ext_vector_type(4))) float;   // MFMA C/D frag

union FragU { bf16x8 f; uint2 u2[2]; uint4 u4; };

// ---- bf16 pack/unpack helpers (RNE) ---------------------------------------
__device__ __forceinline__ unsigned f2bf(float x) {
    union { float f; unsigned u; } v; v.f = x;
    return (v.u + 0x7fffu + ((v.u >> 16) & 1u)) >> 16;
}
__device__ __forceinline__ float bflo(unsigned u) {
    union { unsigned u; float f; } v; v.u = u << 16; return v.f;
}
__device__ __forceinline__ float bfhi(unsigned u) {
    union { unsigned u; float f; } v; v.u = u & 0xffff0000u; return v.f;
}

// ---------------------------------------------------------------------------
// prep_all (614 blocks x 256)  — unchanged from R7.
// ---------------------------------------------------------------------------
__global__ __launch_bounds__(256) void prep_all_kernel(
    const float* __restrict__ Wu, const float* __restrict__ Wi,
    const float* __restrict__ ue, const float* __restrict__ ie,
    const float* __restrict__ gu, const float* __restrict__ gi,
    const float* __restrict__ uu, const float* __restrict__ ui,
    const float* __restrict__ uek, const float* __restrict__ iek,
    unsigned short* __restrict__ Bptu, unsigned short* __restrict__ Bpti,
    unsigned short* __restrict__ Btu, unsigned short* __restrict__ Bti)
{
    __shared__ float T[2][128];                    // only used by EKGU blocks
    int b = blockIdx.x, t = threadIdx.x;
    if (b < 50) {
        int side = b / 25;
        int o = (b % 25) * 256 + t;                 // < 6400
        int d = o / L, l = o % L;
        const float* W = side ? Wi : Wu;
        const float* E = side ? ie : ue;
        unsigned short* Bpt = side ? Bpti : Bptu;
        float a = 0.f;
        for (int k = 0; k < D; ++k) a += W[d * D + k] * E[l * D + k];
        Bpt[(128 + l) * 128 + d] = (unsigned short)f2bf(a);
    } else if (b < 306) {
        int bb = b - 50;
        int side = bb / 128;
        int o = (bb % 128) * 256 + t;               // < 32768
        int r = o >> 7, c = o & 127;                // r 0..255 (GU: 256 rows)
        const float* G = side ? gi : gu;
        const float* U = side ? ui : uu;
        unsigned short* Bt = side ? Bti : Btu;
        float a = 0.f;
        for (int k = 0; k < D; ++k) a += G[r * D + k] * U[k * D + c];
        Bt[c * 448 + r] = (unsigned short)f2bf(a);
    } else if (b < 434) {
        int bb = b - 306;
        int side = bb >> 6;                         // 64 blocks/side
        int o = (bb & 63) * 256 + t;                // < 16384
        int r = o >> 7, c = o & 127;                // r 0..127 (upd_bot)
        const float* U = side ? ui : uu;
        unsigned short* Bt = side ? Bti : Btu;
        Bt[c * 448 + 320 + r] = (unsigned short)f2bf(U[(128 + r) * D + c]);
        if (r < 14) Bt[c * 448 + 306 + r] = 0;
    } else if (b < 562) {
        int bb = b - 434;
        int side = bb >> 6;
        int o = (bb & 63) * 256 + t;                // < 16384
        int k = o >> 7, c = o & 127;
        const float* W = side ? Wi : Wu;
        unsigned short* Bpt = side ? Bpti : Bptu;
        Bpt[c * 128 + k] = (unsigned short)f2bf(W[k * D + c]);
    } else if (b < 564) {
        int side = b - 562;
        unsigned short* Bpt = side ? Bpti : Bptu;
        for (int j = 0; j < 7; ++j)
            Bpt[178 * 128 + t * 7 + j] = 0;
    } else {
        int bb = b - 564;
        int side = bb / 25;
        int ro = (bb % 25) * 2;                     // 2 embk rows per block
        const float* EK = side ? iek : uek;
        const float* G  = side ? gi : gu;
        const float* U  = side ? ui : uu;
        unsigned short* Bt = side ? Bti : Btu;
        int r = t >> 7, c = t & 127;
        float a = 0.f;
        for (int k = 0; k < D; ++k) a += EK[(ro + r) * D + k] * G[k * D + c];
        T[r][c] = a;
        __syncthreads();
        float e = 0.f;
        for (int j = 0; j < D; ++j) e += T[r][j] * U[j * D + c];
        Bt[c * 448 + 256 + ro + r] = (unsigned short)f2bf(e);
    }
}

// ---------------------------------------------------------------------------
// proj_mfma v2: whole Bpt (192x128 bf16) in LDS once; barrier-free K-loop.
// A-frags packed in-register from X (f32 global). 32 rows/block, grid N/32.
// LDS stride 68 u32 -> b128 frag reads <=2-way.
// ---------------------------------------------------------------------------
__global__ __launch_bounds__(256) void proj_mfma(
    const float* __restrict__ Xu, const float* __restrict__ Xi,
    const unsigned* __restrict__ Bptu32, const unsigned* __restrict__ Bpti32,
    unsigned* __restrict__ h32, float* __restrict__ eproj,
    unsigned* __restrict__ A32, int NU)
{
    __shared__ __align__(16) unsigned Bs[192 * 68];     // 52 KB
    int t = threadIdx.x;
    int nb = blockIdx.x * 32;
    const float* X = (nb < NU) ? Xu : Xi;
    int xoff = (nb < NU) ? 0 : NU;
    const unsigned* Bt = (nb < NU) ? Bptu32 : Bpti32;   // [192][64 u32]
    int wave = t >> 6, lane = t & 63;
    int m16 = lane & 15, quad = lane >> 4;

    #pragma unroll
    for (int i = 0; i < 12; ++i) {                      // 3072 uint4
        int idx = t + i * 256;
        int c = idx >> 4, q = idx & 15;
        uint4 v = *(const uint4*)&Bt[(size_t)c * 64 + q * 4];
        *(uint4*)&Bs[c * 68 + q * 4] = v;
    }
    __syncthreads();

    f32x4 acc[2][3];
    for (int i = 0; i < 2; ++i)
        for (int j = 0; j < 3; ++j) acc[i][j] = (f32x4){0.f, 0.f, 0.f, 0.f};

    #pragma unroll
    for (int kc = 0; kc < 4; ++kc) {
        FragU a[2];
        #pragma unroll
        for (int mi = 0; mi < 2; ++mi) {
            int row = nb + mi * 16 + m16;
            const float* src = &X[(size_t)(row - xoff) * D + kc * 32 + quad * 8];
            float4 v0 = *(const float4*)&src[0];
            float4 v1 = *(const float4*)&src[4];
            uint4 pk;
            pk.x = f2bf(v0.x) | (f2bf(v0.y) << 16);
            pk.y = f2bf(v0.z) | (f2bf(v0.w) << 16);
            pk.z = f2bf(v1.x) | (f2bf(v1.y) << 16);
            pk.w = f2bf(v1.z) | (f2bf(v1.w) << 16);
            a[mi].u4 = pk;
            if (wave == 0)                              // one wave writes x->A32
                *(uint4*)&A32[(size_t)row * 224 + 160 + kc * 16 + quad * 4] = pk;
        }
        #pragma unroll
        for (int ni = 0; ni < 3; ++ni) {
            bf16x8 bb = *(const bf16x8*)&Bs[(wave * 48 + ni * 16 + m16) * 68 + kc * 16 + quad * 4];
            acc[0][ni] = __builtin_amdgcn_mfma_f32_16x16x32_bf16(a[0].f, bb, acc[0][ni], 0, 0, 0);
            acc[1][ni] = __builtin_amdgcn_mfma_f32_16x16x32_bf16(a[1].f, bb, acc[1][ni], 0, 0, 0);
        }
    }
    // epilogue: C/D layout col=lane&15, row=quad*4+r
    #pragma unroll
    for (int mi = 0; mi < 2; ++mi)
        #pragma unroll
        for (int ni = 0; ni < 3; ++ni) {
            int col = wave * 48 + ni * 16 + m16;
            #pragma unroll
            for (int r = 0; r < 4; ++r) {
                float me = acc[mi][ni][r];
                float pr = __shfl_xor(me, 1);           // partner col (lane^1)
                int row = nb + mi * 16 + quad * 4 + r;
                if (col < 128) {
                    if (!(lane & 1))
                        h32[(size_t)row * 64 + (col >> 1)] = f2bf(me) | (f2bf(pr) << 16);
                } else if (col < 178) {
                    eproj[(size_t)row * L + (col - 128)] = me;
                }
            }
        }
}

// ---------------------------------------------------------------------------
// agg — unchanged from R7.
// ---------------------------------------------------------------------------
__global__ __launch_bounds__(256) void agg_kernel(
    const unsigned* __restrict__ h32, const float* __restrict__ eproj,
    const int* __restrict__ unbr, const int* __restrict__ untime,
    const int* __restrict__ inbr, const int* __restrict__ intime,
    unsigned* __restrict__ A32, int NU, int NI)
{
    __shared__ unsigned smail[2][L * 66];     // bf16x2, stride 66 u32
    __shared__ unsigned shb[2][64];           // h packed bf16
    __shared__ float se2[2][2][64];           // [long/short][slot]
    __shared__ float salpha[2][L], salpha1[2][L];
    __shared__ int stime[2][L], sreorder[2][L], snbr[2][L], slast[2];

    int tb = threadIdx.x;
    int sub = tb >> 7;                  // node slot 0/1
    int t = tb & 127;                   // within-node tid
    int g = blockIdx.x * 2 + sub;       // global node
    int wave = t >> 6, lane = t & 63;
    int m16 = lane & 15, quad = lane >> 4;

    const unsigned* mail; const int* nbrp; const int* timp;
    if (g < NU) { mail = h32 + (size_t)NU * 64; nbrp = unbr + (size_t)g * L;        timp = untime + (size_t)g * L; }
    else        { mail = h32;                   nbrp = inbr + (size_t)(g - NU) * L; timp = intime + (size_t)(g - NU) * L; }

    if (t < 64) shb[sub][t] = h32[(size_t)g * 64 + t];
    if (t < L) { stime[sub][t] = timp[t]; snbr[sub][t] = nbrp[t]; }
    __syncthreads();

    // ranks (stable argsort∘argsort) + first-occurrence argmax
    if (t < L) {
        int ti = stime[sub][t]; int rank = 0; bool firstmax = true;
        for (int j = 0; j < L; ++j) {
            int tj = stime[sub][j];
            rank += (tj < ti) || (tj == ti && j < t);
            firstmax = firstmax && ((tj < ti) || (tj == ti && j >= t));
        }
        sreorder[sub][t] = L - 1 - rank;
        if (firstmax) slast[sub] = t;
    }
    // stage mail: uint2 global copy -> LDS stride 66 (no convert)
    {
        int q = t >> 5, p = t & 31;     // row group, pair index
        #pragma unroll
        for (int i = 0; i < 13; ++i) {
            int l = i * 4 + q;
            if (l < L) {
                uint2 v = *(const uint2*)&mail[(size_t)snbr[sub][l] * 64 + p * 2];
                *(uint2*)&smail[sub][l * 66 + 2 * p] = v;
            }
        }
    }
    __syncthreads();

    // scores via MFMA: col0 = mail.h (long), col1 = mail.last
    {
        const unsigned* bptr = (m16 == 1) ? &smail[sub][slast[sub] * 66]
                                          : &shb[sub][0];
        int s0 = wave * 32 + m16;  if (s0 > 49) s0 = 49;
        int s1 = wave * 32 + 16 + m16;  if (s1 > 49) s1 = 49;
        const unsigned* a0p = &smail[sub][s0 * 66];
        const unsigned* a1p = &smail[sub][s1 * 66];
        f32x4 d0 = {0.f, 0.f, 0.f, 0.f}, d1 = {0.f, 0.f, 0.f, 0.f};
        #pragma unroll
        for (int kc = 0; kc < 4; ++kc) {
            int off = kc * 16 + quad * 4;
            FragU bf_, af0, af1;
            bf_.u2[0] = *(const uint2*)&bptr[off];
            bf_.u2[1] = *(const uint2*)&bptr[off + 2];
            af0.u2[0] = *(const uint2*)&a0p[off];
            af0.u2[1] = *(const uint2*)&a0p[off + 2];
            af1.u2[0] = *(const uint2*)&a1p[off];
            af1.u2[1] = *(const uint2*)&a1p[off + 2];
            d0 = __builtin_amdgcn_mfma_f32_16x16x32_bf16(af0.f, bf_.f, d0, 0, 0, 0);
            d1 = __builtin_amdgcn_mfma_f32_16x16x32_bf16(af1.f, bf_.f, d1, 0, 0, 0);
        }
        if (m16 < 2) {                   // redistribute: row=quad*4+r, col=m16
            #pragma unroll
            for (int r = 0; r < 4; ++r) {
                se2[sub][m16][wave * 32 + quad * 4 + r]      = d0[r];
                se2[sub][m16][wave * 32 + 16 + quad * 4 + r] = d1[r];
            }
        }
    }
    __syncthreads();

    // softmax: wave0 long (+eproj), wave1 short
    float sc = -1e30f;
    if (lane < L) {
        sc = (wave == 0)
           ? (se2[sub][0][lane] + eproj[(size_t)g * L + sreorder[sub][lane]]) * SCALE
           : se2[sub][1][lane] * SCALE;
    }
    float mx = sc;
    for (int off = 32; off; off >>= 1) mx = fmaxf(mx, __shfl_xor(mx, off));
    float ex = (lane < L) ? expf(sc - mx) : 0.f;
    float sm = ex;
    for (int off = 32; off; off >>= 1) sm += __shfl_xor(sm, off);
    float al = ex / sm;
    if (lane < L) { if (wave == 0) salpha[sub][lane] = al; else salpha1[sub][lane] = al; }
    __syncthreads();

    // weighted sums: wave0 -> hl word lane, wave1 -> hs word lane (linear addr)
    {
        const float* alp = wave ? salpha1[sub] : salpha[sub];
        const unsigned* base = &smail[sub][lane];
        float ax = 0.f, ay = 0.f;
        for (int l = 0; l < L; ++l) {
            unsigned u = base[l * 66];
            float a = alp[l];
            ax += a * bflo(u);
            ay += a * bfhi(u);
        }
        A32[(size_t)g * 224 + wave * 64 + lane] = f2bf(ax) | (f2bf(ay) << 16);
    }
    if (t >= 64 && t < 96) A32[(size_t)g * 224 + 128 + (t - 64)] = 0u;
    __syncthreads();
    if (t < L) {
        ((unsigned short*)A32)[(size_t)g * 448 + 256 + sreorder[sub][t]] =
            (unsigned short)f2bf(salpha[sub][t]);
    }
}

// ---------------------------------------------------------------------------
// gemm_out v2: block = 128 rows x 64 cols; B col-half (64x448 bf16) in LDS
// once; barrier-free K-loop with A-frags straight from global A32.
// Wave: 2 m-tiles x 4 n-frags. Grid (N/128)*2. LDS stride 228 u32.
// ---------------------------------------------------------------------------
__global__ __launch_bounds__(256) void gemm_out_mfma(
    const unsigned* __restrict__ A32,
    const unsigned* __restrict__ Btu32, const unsigned* __restrict__ Bti32,
    float* __restrict__ out, int NU)
{
    __shared__ __align__(16) unsigned Bs[64 * 228];     // 57 KB
    int t = threadIdx.x;
    int rowblk = blockIdx.x >> 1, half = blockIdx.x & 1;
    int nb = rowblk * 128;
    const unsigned* Bt = (nb < NU) ? Btu32 : Bti32;     // [128 n][224 u32]
    int wave = t >> 6, lane = t & 63;
    int m16 = lane & 15, quad = lane >> 4;

    #pragma unroll
    for (int i = 0; i < 14; ++i) {                      // 3584 uint4
        int idx = t + i * 256;
        int n = idx / 56, q = idx - n * 56;             // 56 uint4 per row
        uint4 v = *(const uint4*)&Bt[(size_t)(half * 64 + n) * 224 + q * 4];
        *(uint4*)&Bs[n * 228 + q * 4] = v;
    }
    __syncthreads();

    #pragma unroll
    for (int j = 0; j < 2; ++j) {
        int mrow0 = nb + (wave * 2 + j) * 16;
        f32x4 acc[4] = {{0.f,0.f,0.f,0.f},{0.f,0.f,0.f,0.f},
                        {0.f,0.f,0.f,0.f},{0.f,0.f,0.f,0.f}};
        for (int kc = 0; kc < 14; ++kc) {
            FragU af;
            af.u4 = *(const uint4*)&A32[(size_t)(mrow0 + m16) * 224 + kc * 16 + quad * 4];
            #pragma unroll
            for (int ni = 0; ni < 4; ++ni) {
                bf16x8 bf = *(const bf16x8*)&Bs[(ni * 16 + m16) * 228 + kc * 16 + quad * 4];
                acc[ni] = __builtin_amdgcn_mfma_f32_16x16x32_bf16(af.f, bf, acc[ni], 0, 0, 0);
            }
        }
        #pragma unroll
        for (int ni = 0; ni < 4; ++ni)
            #pragma unroll
            for (int r = 0; r < 4; ++r) {
                int row = mrow0 + quad * 4 + r;
                int col = half * 64 + ni * 16 + m16;
                out[(size_t)row * D + col] = tanhf(acc[ni][r]);
            }
    }
}

// ---------------------------------------------------------------------------
extern "C" void kernel_launch(void* const* d_in, const int* in_sizes, int n_in,
                              void* d_out, int out_size, void* d_ws, size_t ws_size,
                              hipStream_t stream) {
    const float* user   = (const float*)d_in[0];
    const float* item   = (const float*)d_in[1];
    const float* Wu     = (const float*)d_in[2];
    const float* Wi     = (const float*)d_in[3];
    const float* gate_u = (const float*)d_in[4];
    const float* gate_i = (const float*)d_in[5];
    const float* upd_u  = (const float*)d_in[6];
    const float* upd_i  = (const float*)d_in[7];
    const float* uemb   = (const float*)d_in[8];
    const float* uembk  = (const float*)d_in[9];
    const float* iemb   = (const float*)d_in[10];
    const float* iembk  = (const float*)d_in[11];
    const int*   unbr   = (const int*)d_in[12];
    const int*   untime = (const int*)d_in[13];
    const int*   inbr   = (const int*)d_in[14];
    const int*   intime = (const int*)d_in[15];

    int NU = in_sizes[0] / D;
    int NI = in_sizes[1] / D;
    int N  = NU + NI;

    float* eproj  = (float*)d_ws;                   // N*50 f32
    unsigned* h32   = (unsigned*)(eproj + (size_t)N * L);  // N*64 u32
    unsigned* A32   = h32 + (size_t)N * 64;         // N*224 u32 (bf16 A)
    unsigned* Btu32 = A32 + (size_t)N * 224;        // 128*224 u32 each
    unsigned* Bti32 = Btu32 + 128 * 224;
    unsigned* Bptu32 = Bti32 + 128 * 224;           // 192*64 u32 each
    unsigned* Bpti32 = Bptu32 + 192 * 64;

    prep_all_kernel<<<614, 256, 0, stream>>>(Wu, Wi, uemb, iemb, gate_u, gate_i,
                                             upd_u, upd_i, uembk, iembk,
                                             (unsigned short*)Bptu32,
                                             (unsigned short*)Bpti32,
                                             (unsigned short*)Btu32,
                                             (unsigned short*)Bti32);
    proj_mfma<<<N / 32, 256, 0, stream>>>(user, item, Bptu32, Bpti32,
                                          h32, eproj, A32, NU);
    agg_kernel<<<N / 2, 256, 0, stream>>>(h32, eproj, unbr, untime, inbr,
                                          intime, A32, NU, NI);
    gemm_out_mfma<<<N / 64, 256, 0, stream>>>(A32, Btu32, Bti32,
                                              (float*)d_out, NU);
}